// Round 4
// baseline (1498.023 us; speedup 1.0000x reference)
//
#include <hip/hip_runtime.h>
#include <hip/hip_bf16.h>
#include <cmath>

#define DEV static __device__ __forceinline__

constexpr int NN = 100000;
constexpr int NE = 1600000;
constexpr int D  = 128;
constexpr int SCHUNK = 1024;
constexpr int NBS = (NN + SCHUNK - 1) / SCHUNK;   // 98

DEV float bf2f(unsigned short u) {
    unsigned int t = ((unsigned int)u) << 16;
    return __builtin_bit_cast(float, t);
}
DEV unsigned short f2bf(float f) {
    unsigned int u = __builtin_bit_cast(unsigned int, f);
    u += 0x7fffu + ((u >> 16) & 1u);
    return (unsigned short)(u >> 16);
}
DEV float bfx(const uint2& q, int j) {
    unsigned int w = (j & 2) ? q.y : q.x;
    unsigned short h = (j & 1) ? (unsigned short)(w >> 16) : (unsigned short)(w & 0xffffu);
    return bf2f(h);
}
DEV unsigned int packbf(float a, float b) {
    return (unsigned int)f2bf(a) | ((unsigned int)f2bf(b) << 16);
}

// typed helpers: storage may be f32 or bf16(ushort)
DEV void load4f(const float* p, float o[4]) {
    float4 v = *(const float4*)p;
    o[0] = v.x; o[1] = v.y; o[2] = v.z; o[3] = v.w;
}
DEV void load4f(const unsigned short* p, float o[4]) {
    uint2 q = *(const uint2*)p;
    o[0] = bfx(q, 0); o[1] = bfx(q, 1); o[2] = bfx(q, 2); o[3] = bfx(q, 3);
}
DEV void load2f(const float* p, float& a, float& b) {
    float2 v = *(const float2*)p; a = v.x; b = v.y;
}
DEV void load2f(const unsigned short* p, float& a, float& b) {
    unsigned int w = *(const unsigned int*)p;
    a = bf2f((unsigned short)(w & 0xffffu));
    b = bf2f((unsigned short)(w >> 16));
}
DEV void store2(float* p, float a, float b) { *(float2*)p = make_float2(a, b); }
DEV void store2(unsigned short* p, float a, float b) { *(unsigned int*)p = packbf(a, b); }

// ---- int-width detection ----
// flags[1]: edge_index int64?  flags[2]: y int64?  flags[3]: mask 0=int32,1=int64,2=uint8
__global__ void k_detect(const unsigned int* __restrict__ ew,
                         const unsigned int* __restrict__ yw,
                         const unsigned int* __restrict__ mw,
                         int* __restrict__ flags) {
    if (threadIdx.x != 0 || blockIdx.x != 0) return;
    int nz = 0;
    for (int i = 0; i < 64; i++) if (ew[2 * i + 1] != 0u) nz++;
    flags[1] = (nz < 8) ? 1 : 0;
    nz = 0;
    for (int i = 0; i < 64; i++) if (yw[2 * i + 1] != 0u) nz++;
    flags[2] = (nz < 8) ? 1 : 0;
    int big = 0; nz = 0;
    for (int i = 0; i < 64; i++) if (mw[i] > 1u) big++;
    for (int i = 0; i < 64; i++) if (mw[2 * i + 1] != 0u) nz++;
    flags[3] = big > 8 ? 2 : (nz < 8 ? 1 : 0);
}

__global__ void k_conv_e(const int* __restrict__ flg, const void* __restrict__ ei,
                         int* __restrict__ SRC, int* __restrict__ DST) {
    int e = blockIdx.x * blockDim.x + threadIdx.x;
    if (e >= NE) return;
    if (flg[1]) {
        const long long* p = (const long long*)ei;
        SRC[e] = (int)p[e];
        DST[e] = (int)p[NE + e];
    } else {
        const int* p = (const int*)ei;
        SRC[e] = p[e];
        DST[e] = p[NE + e];
    }
}

__global__ void k_prep(const int* __restrict__ flg, const void* __restrict__ y,
                       const void* __restrict__ mask, int* __restrict__ nt) {
    int i = blockIdx.x * blockDim.x + threadIdx.x;
    if (i >= NN) return;
    int yv = flg[2] ? (int)((const long long*)y)[i] : ((const int*)y)[i];
    int mm = flg[3] == 2 ? (int)((const unsigned char*)mask)[i]
           : flg[3] == 1 ? (int)((const long long*)mask)[i]
           : ((const int*)mask)[i];
    nt[i] = mm ? yv : 2;
}

// ---- CSR build ----
__global__ void k_hist(const int* __restrict__ DST, int* __restrict__ deg) {
    for (int e = blockIdx.x * blockDim.x + threadIdx.x; e < NE; e += gridDim.x * blockDim.x)
        atomicAdd(&deg[DST[e]], 1);
}

__global__ void k_scan_a(const int* __restrict__ deg, int* __restrict__ bsum) {
    __shared__ int sh[256];
    int b = blockIdx.x, t = threadIdx.x;
    int base = b * SCHUNK + t * 4;
    int s = 0;
#pragma unroll
    for (int j = 0; j < 4; j++) { int i = base + j; if (i < NN) s += deg[i]; }
    sh[t] = s; __syncthreads();
    for (int d = 128; d > 0; d >>= 1) {
        if (t < d) sh[t] += sh[t + d];
        __syncthreads();
    }
    if (t == 0) bsum[b] = sh[0];
}

__global__ void k_scan_b(const int* __restrict__ bsum, int* __restrict__ bpre,
                         int* __restrict__ offs) {
    __shared__ int sh[128];
    int t = threadIdx.x;
    int v = (t < NBS) ? bsum[t] : 0;
    int incl = v; sh[t] = incl; __syncthreads();
    for (int d = 1; d < 128; d <<= 1) {
        int add = (t >= d) ? sh[t - d] : 0;
        __syncthreads();
        incl += add; sh[t] = incl;
        __syncthreads();
    }
    if (t < NBS) bpre[t] = incl - v;
    if (t == 0) offs[NN] = NE;
}

__global__ void k_scan_c(const int* __restrict__ deg, const int* __restrict__ bpre,
                         int* __restrict__ offs) {
    __shared__ int sh[256];
    int b = blockIdx.x, t = threadIdx.x;
    int base = b * SCHUNK + t * 4;
    int v[4];
#pragma unroll
    for (int j = 0; j < 4; j++) { int i = base + j; v[j] = (i < NN) ? deg[i] : 0; }
    int tsum = v[0] + v[1] + v[2] + v[3];
    int incl = tsum; sh[t] = incl; __syncthreads();
    for (int d = 1; d < 256; d <<= 1) {
        int add = (t >= d) ? sh[t - d] : 0;
        __syncthreads();
        incl += add; sh[t] = incl;
        __syncthreads();
    }
    int ex = (incl - tsum) + bpre[b];
#pragma unroll
    for (int j = 0; j < 4; j++) {
        int i = base + j;
        if (i < NN) { offs[i] = ex; ex += v[j]; }
    }
}

__global__ void k_place(const int* __restrict__ SRC, const int* __restrict__ DST,
                        const int* __restrict__ offs, int* __restrict__ cur,
                        int* __restrict__ ssrc) {
    for (int e = blockIdx.x * blockDim.x + threadIdx.x; e < NE; e += gridDim.x * blockDim.x) {
        int d = DST[e];
        int p = offs[d] + atomicAdd(&cur[d], 1);
        ssrc[p] = SRC[e];
    }
}

// ---- per-destination aggregation (one wave per node) ----
// U[d] = sum_{src:nt=1} x_src + a_d * sum_{src:nt=2} x_src
// V[d] = sum_{src:nt=0} x_src + (1-a_d) * sum_{src:nt=2} x_src
template<typename XT, typename UVT>
__global__ void __launch_bounds__(256)
k_aggr(const XT* __restrict__ X, const int* __restrict__ ssrc,
       const int* __restrict__ offs, const int* __restrict__ nt,
       const float* __restrict__ aw, const float* __restrict__ ab,
       UVT* __restrict__ U, UVT* __restrict__ V) {
    int lane = threadIdx.x & 63;
    int d = blockIdx.x * (blockDim.x >> 6) + (threadIdx.x >> 6);
    if (d >= NN) return;
    int k0 = lane * 2;

    float xa, xb;
    load2f(X + (size_t)d * D + k0, xa, xb);
    float dot = xa * aw[k0] + xb * aw[k0 + 1];
#pragma unroll
    for (int m = 32; m > 0; m >>= 1) dot += __shfl_xor(dot, m, 64);
    float a = 1.0f / (1.0f + expf(-(dot + ab[0])));
    float oma = 1.0f - a;

    float u0 = 0.f, u1 = 0.f, v0 = 0.f, v1 = 0.f;
    int e0 = offs[d], e1 = offs[d + 1];
    for (int e = e0; e < e1; e++) {
        int s = ssrc[e];
        int b = nt[s];
        float x0, x1;
        load2f(X + (size_t)s * D + k0, x0, x1);
        if (b == 1)      { u0 += x0; u1 += x1; }
        else if (b == 0) { v0 += x0; v1 += x1; }
        else             { u0 += a * x0; u1 += a * x1; v0 += oma * x0; v1 += oma * x1; }
    }
    store2(U + (size_t)d * D + k0, u0, u1);
    store2(V + (size_t)d * D + k0, v0, v1);
}

// ---- fused layer GEMM: out = relu(U@Wfr + V@Wbe + X@Wself + b), 8 rows/wave ----
template<typename XT, typename UVT, typename OT>
__global__ void __launch_bounds__(256)
k_gemm(const XT* __restrict__ X, const UVT* __restrict__ U, const UVT* __restrict__ V,
       const float* __restrict__ Wfr, const float* __restrict__ Wbe,
       const float* __restrict__ Wsf, const float* __restrict__ bias,
       OT* __restrict__ out) {
    int lane = threadIdx.x & 63;
    int wave = threadIdx.x >> 6;
    int r0 = blockIdx.x * 32 + wave * 8;
    if (r0 >= NN) return;
    int c = lane * 2;

    float bc0 = bias[c], bc1 = bias[c + 1];
    float acc[8][2];
#pragma unroll
    for (int r = 0; r < 8; r++) { acc[r][0] = bc0; acc[r][1] = bc1; }

    for (int k4 = 0; k4 < D; k4 += 4) {
        float xs[8][4], us[8][4], vs[8][4];
#pragma unroll
        for (int r = 0; r < 8; r++) {
            load4f(X + (size_t)(r0 + r) * D + k4, xs[r]);
            load4f(U + (size_t)(r0 + r) * D + k4, us[r]);
            load4f(V + (size_t)(r0 + r) * D + k4, vs[r]);
        }
#pragma unroll
        for (int j = 0; j < 4; j++) {
            int k = k4 + j;
            float2 wf = *(const float2*)(Wfr + (size_t)k * D + c);
            float2 wb = *(const float2*)(Wbe + (size_t)k * D + c);
            float2 wsv = *(const float2*)(Wsf + (size_t)k * D + c);
#pragma unroll
            for (int r = 0; r < 8; r++) {
                acc[r][0] += us[r][j] * wf.x + vs[r][j] * wb.x + xs[r][j] * wsv.x;
                acc[r][1] += us[r][j] * wf.y + vs[r][j] * wb.y + xs[r][j] * wsv.y;
            }
        }
    }
#pragma unroll
    for (int r = 0; r < 8; r++) {
        float a0 = fmaxf(acc[r][0], 0.f);
        float a1 = fmaxf(acc[r][1], 0.f);
        store2(out + (size_t)(r0 + r) * D + c, a0, a1);
    }
}

// ---- classifier: out[N,8] f32 ----
template<typename HT>
__global__ void __launch_bounds__(256)
k_cls(const HT* __restrict__ H, const float* __restrict__ W,
      const float* __restrict__ b, float* __restrict__ out) {
    int lane = threadIdx.x & 63;
    int wid = blockIdx.x * (blockDim.x >> 6) + (threadIdx.x >> 6);
    if (wid >= NN) return;
    int cc = lane & 7;
    int kg = lane >> 3;
    const HT* hr = H + (size_t)wid * D + kg * 16;
    float s = 0.f;
#pragma unroll
    for (int j = 0; j < 16; j += 2) {
        float h0, h1;
        load2f(hr + j, h0, h1);
        s += h0 * W[(kg * 16 + j) * 8 + cc];
        s += h1 * W[(kg * 16 + j + 1) * 8 + cc];
    }
    s += __shfl_xor(s, 8, 64);
    s += __shfl_xor(s, 16, 64);
    s += __shfl_xor(s, 32, 64);
    if (lane < 8) out[(size_t)wid * 8 + cc] = s + b[cc];
}

template<typename IT>
static void run_pipeline(const float* x, const int* SSRC, const int* OFFS,
                         const int* NT, void* const* d_in,
                         IT* U, IT* V, IT* H, IT* H2, float* out, hipStream_t stream) {
    const float* aw1 = (const float*)d_in[6];
    const float* ab1 = (const float*)d_in[7];
    const float* aw2 = (const float*)d_in[12];
    const float* ab2 = (const float*)d_in[13];
    k_aggr<float, IT><<<NN / 4, 256, 0, stream>>>(x, SSRC, OFFS, NT, aw1, ab1, U, V);
    k_gemm<float, IT, IT><<<NN / 32, 256, 0, stream>>>(x, U, V,
        (const float*)d_in[4], (const float*)d_in[5], (const float*)d_in[8],
        (const float*)d_in[9], H);
    k_aggr<IT, IT><<<NN / 4, 256, 0, stream>>>(H, SSRC, OFFS, NT, aw2, ab2, U, V);
    k_gemm<IT, IT, IT><<<NN / 32, 256, 0, stream>>>(H, U, V,
        (const float*)d_in[10], (const float*)d_in[11], (const float*)d_in[14],
        (const float*)d_in[15], H2);
    k_cls<IT><<<NN / 4, 256, 0, stream>>>(H2, (const float*)d_in[16],
        (const float*)d_in[17], out);
}

extern "C" void kernel_launch(void* const* d_in, const int* in_sizes, int n_in,
                              void* d_out, int out_size, void* d_ws, size_t ws_size,
                              hipStream_t stream) {
    const float* x   = (const float*)d_in[0];
    const void* ei   = d_in[1];
    const void* y    = d_in[2];
    const void* mask = d_in[3];

    char* ws = (char*)d_ws;
    size_t cur_off = 0;
    auto alloc = [&](size_t bytes) {
        size_t o = cur_off;
        cur_off = (cur_off + bytes + 255) & ~(size_t)255;
        return o;
    };

    // f32 intermediates need ~180 MB; fall back to bf16 intermediates otherwise
    bool f32tier = (ws_size == 0) || (ws_size >= (size_t)185 * 1000 * 1000);
    size_t esz = f32tier ? 4 : 2;

    size_t oU  = alloc((size_t)NN * D * esz);
    size_t oV  = alloc((size_t)NN * D * esz);
    size_t oH  = alloc((size_t)NN * D * esz);
    size_t oH2 = alloc((size_t)NN * D * esz);
    size_t oNT = alloc(NN * 4);
    size_t oDEG = alloc(NN * 4);
    size_t oOFFS = alloc((NN + 1) * 4);
    size_t oCUR = alloc(NN * 4);
    size_t oBSUM = alloc(NBS * 4);
    size_t oBPRE = alloc(NBS * 4);
    size_t oSSRC = alloc((size_t)NE * 4);
    size_t oSRC = alloc((size_t)NE * 4);
    size_t oDST = alloc((size_t)NE * 4);
    size_t oFLG = alloc(256);

    int* NT   = (int*)(ws + oNT);
    int* DEG  = (int*)(ws + oDEG);
    int* OFFS = (int*)(ws + oOFFS);
    int* CURB = (int*)(ws + oCUR);
    int* BSUM = (int*)(ws + oBSUM);
    int* BPRE = (int*)(ws + oBPRE);
    int* SSRC = (int*)(ws + oSSRC);
    int* SRC  = (int*)(ws + oSRC);
    int* DST  = (int*)(ws + oDST);
    int* FLG  = (int*)(ws + oFLG);

    hipMemsetAsync(DEG, 0, NN * sizeof(int), stream);
    hipMemsetAsync(CURB, 0, NN * sizeof(int), stream);

    k_detect<<<1, 64, 0, stream>>>((const unsigned int*)ei, (const unsigned int*)y,
                                   (const unsigned int*)mask, FLG);
    k_conv_e<<<(NE + 255) / 256, 256, 0, stream>>>(FLG, ei, SRC, DST);
    k_prep<<<(NN + 255) / 256, 256, 0, stream>>>(FLG, y, mask, NT);

    k_hist<<<2048, 256, 0, stream>>>(DST, DEG);
    k_scan_a<<<NBS, 256, 0, stream>>>(DEG, BSUM);
    k_scan_b<<<1, 128, 0, stream>>>(BSUM, BPRE, OFFS);
    k_scan_c<<<NBS, 256, 0, stream>>>(DEG, BPRE, OFFS);
    k_place<<<2048, 256, 0, stream>>>(SRC, DST, OFFS, CURB, SSRC);

    if (f32tier) {
        run_pipeline<float>(x, SSRC, OFFS, NT, d_in,
            (float*)(ws + oU), (float*)(ws + oV), (float*)(ws + oH),
            (float*)(ws + oH2), (float*)d_out, stream);
    } else {
        run_pipeline<unsigned short>(x, SSRC, OFFS, NT, d_in,
            (unsigned short*)(ws + oU), (unsigned short*)(ws + oV),
            (unsigned short*)(ws + oH), (unsigned short*)(ws + oH2),
            (float*)d_out, stream);
    }
}

// Round 5
// 744.443 us; speedup vs baseline: 2.0123x; 2.0123x over previous
//
#include <hip/hip_runtime.h>
#include <hip/hip_bf16.h>
#include <cmath>

#define DEV static __device__ __forceinline__

constexpr int NN = 100000;
constexpr int NE = 1600000;
constexpr int D  = 128;
constexpr int KTOT = 384;          // [X | U | V]
constexpr int SCHUNK = 1024;
constexpr int NBS = (NN + SCHUNK - 1) / SCHUNK;   // 98

typedef __attribute__((ext_vector_type(8))) short short8;
typedef __attribute__((ext_vector_type(4))) float f32x4;

DEV float bf2f(unsigned short u) {
    unsigned int t = ((unsigned int)u) << 16;
    return __builtin_bit_cast(float, t);
}
DEV unsigned short f2bf(float f) {
    unsigned int u = __builtin_bit_cast(unsigned int, f);
    u += 0x7fffu + ((u >> 16) & 1u);   // RNE
    return (unsigned short)(u >> 16);
}
DEV unsigned int packbf(float a, float b) {
    return (unsigned int)f2bf(a) | ((unsigned int)f2bf(b) << 16);
}

// ---- int-width detection (proven in round 4) ----
__global__ void k_detect(const unsigned int* __restrict__ ew,
                         const unsigned int* __restrict__ yw,
                         const unsigned int* __restrict__ mw,
                         int* __restrict__ flags) {
    if (threadIdx.x != 0 || blockIdx.x != 0) return;
    int nz = 0;
    for (int i = 0; i < 64; i++) if (ew[2 * i + 1] != 0u) nz++;
    flags[1] = (nz < 8) ? 1 : 0;
    nz = 0;
    for (int i = 0; i < 64; i++) if (yw[2 * i + 1] != 0u) nz++;
    flags[2] = (nz < 8) ? 1 : 0;
    int big = 0; nz = 0;
    for (int i = 0; i < 64; i++) if (mw[i] > 1u) big++;
    for (int i = 0; i < 64; i++) if (mw[2 * i + 1] != 0u) nz++;
    flags[3] = big > 8 ? 2 : (nz < 8 ? 1 : 0);
}

__global__ void k_prep(const int* __restrict__ flg, const void* __restrict__ y,
                       const void* __restrict__ mask, int* __restrict__ nt) {
    int i = blockIdx.x * blockDim.x + threadIdx.x;
    if (i >= NN) return;
    int yv = flg[2] ? (int)((const long long*)y)[i] : ((const int*)y)[i];
    int mm = flg[3] == 2 ? (int)((const unsigned char*)mask)[i]
           : flg[3] == 1 ? (int)((const long long*)mask)[i]
           : ((const int*)mask)[i];
    nt[i] = mm ? yv : 2;
}

// edges -> packed src ((s<<2)|nt[s]) and dst
__global__ void k_conv_e(const int* __restrict__ flg, const void* __restrict__ ei,
                         const int* __restrict__ nt,
                         int* __restrict__ SP, int* __restrict__ DST) {
    int e = blockIdx.x * blockDim.x + threadIdx.x;
    if (e >= NE) return;
    int s, d;
    if (flg[1]) {
        const long long* p = (const long long*)ei;
        s = (int)p[e]; d = (int)p[NE + e];
    } else {
        const int* p = (const int*)ei;
        s = p[e]; d = p[NE + e];
    }
    SP[e] = (s << 2) | nt[s];
    DST[e] = d;
}

// x (f32) -> A hi/lo planes, cols 0..127 of stride-384 rows
__global__ void k_convx(const float* __restrict__ x,
                        unsigned short* __restrict__ Ahi, unsigned short* __restrict__ Alo) {
    long t = blockIdx.x * (long)blockDim.x + threadIdx.x;
    long g = t * 4;
    if (g >= (long)NN * D) return;
    int n = (int)(g >> 7);
    int k = (int)(g & 127);
    float4 v = *(const float4*)(x + g);
    float vv[4] = {v.x, v.y, v.z, v.w};
    ushort4 hi, lo;
    unsigned short* hp = (unsigned short*)&hi;
    unsigned short* lp = (unsigned short*)&lo;
#pragma unroll
    for (int j = 0; j < 4; j++) {
        unsigned short h = f2bf(vv[j]);
        hp[j] = h;
        lp[j] = f2bf(vv[j] - bf2f(h));
    }
    size_t dst = (size_t)n * KTOT + k;
    *(ushort4*)(Ahi + dst) = hi;
    *(ushort4*)(Alo + dst) = lo;
}

// weights -> B-fragment-ordered hi/lo planes.
// Wcat[k][c]: k<128 -> Wself, k<256 -> Wfr, else Wbe. Frag index:
// ((kt*8+ct)*64 + lane)*8 + j  with k = kt*32 + (lane>>4)*8 + j, c = ct*16 + (lane&15)
__global__ void k_wprep(const float* __restrict__ Wsf, const float* __restrict__ Wfr,
                        const float* __restrict__ Wbe,
                        unsigned short* __restrict__ WpHi, unsigned short* __restrict__ WpLo) {
    int t = blockIdx.x * blockDim.x + threadIdx.x;
    if (t >= KTOT * D) return;
    int k = t >> 7;
    int c = t & 127;
    float w = k < 128 ? Wsf[k * 128 + c]
            : k < 256 ? Wfr[(k - 128) * 128 + c]
            : Wbe[(k - 256) * 128 + c];
    unsigned short hi = f2bf(w);
    unsigned short lo = f2bf(w - bf2f(hi));
    int kt = k >> 5, kin = k & 31;
    int grp = kin >> 3, j = kin & 7;
    int ct = c >> 4, cl = c & 15;
    size_t idx = (((size_t)kt * 8 + ct) * 64 + ((grp << 4) | cl)) * 8 + j;
    WpHi[idx] = hi;
    WpLo[idx] = lo;
}

// ---- CSR build ----
__global__ void k_hist(const int* __restrict__ DST, int* __restrict__ deg) {
    for (int e = blockIdx.x * blockDim.x + threadIdx.x; e < NE; e += gridDim.x * blockDim.x)
        atomicAdd(&deg[DST[e]], 1);
}

__global__ void k_scan_a(const int* __restrict__ deg, int* __restrict__ bsum) {
    __shared__ int sh[256];
    int b = blockIdx.x, t = threadIdx.x;
    int base = b * SCHUNK + t * 4;
    int s = 0;
#pragma unroll
    for (int j = 0; j < 4; j++) { int i = base + j; if (i < NN) s += deg[i]; }
    sh[t] = s; __syncthreads();
    for (int d = 128; d > 0; d >>= 1) {
        if (t < d) sh[t] += sh[t + d];
        __syncthreads();
    }
    if (t == 0) bsum[b] = sh[0];
}

__global__ void k_scan_b(const int* __restrict__ bsum, int* __restrict__ bpre,
                         int* __restrict__ offs) {
    __shared__ int sh[128];
    int t = threadIdx.x;
    int v = (t < NBS) ? bsum[t] : 0;
    int incl = v; sh[t] = incl; __syncthreads();
    for (int d = 1; d < 128; d <<= 1) {
        int add = (t >= d) ? sh[t - d] : 0;
        __syncthreads();
        incl += add; sh[t] = incl;
        __syncthreads();
    }
    if (t < NBS) bpre[t] = incl - v;
    if (t == 0) offs[NN] = NE;
}

__global__ void k_scan_c(const int* __restrict__ deg, const int* __restrict__ bpre,
                         int* __restrict__ offs) {
    __shared__ int sh[256];
    int b = blockIdx.x, t = threadIdx.x;
    int base = b * SCHUNK + t * 4;
    int v[4];
#pragma unroll
    for (int j = 0; j < 4; j++) { int i = base + j; v[j] = (i < NN) ? deg[i] : 0; }
    int tsum = v[0] + v[1] + v[2] + v[3];
    int incl = tsum; sh[t] = incl; __syncthreads();
    for (int d = 1; d < 256; d <<= 1) {
        int add = (t >= d) ? sh[t - d] : 0;
        __syncthreads();
        incl += add; sh[t] = incl;
        __syncthreads();
    }
    int ex = (incl - tsum) + bpre[b];
#pragma unroll
    for (int j = 0; j < 4; j++) {
        int i = base + j;
        if (i < NN) { offs[i] = ex; ex += v[j]; }
    }
}

__global__ void k_place(const int* __restrict__ SP, const int* __restrict__ DST,
                        const int* __restrict__ offs, int* __restrict__ cur,
                        int* __restrict__ ssrc) {
    for (int e = blockIdx.x * blockDim.x + threadIdx.x; e < NE; e += gridDim.x * blockDim.x) {
        int d = DST[e];
        int p = offs[d] + atomicAdd(&cur[d], 1);
        ssrc[p] = SP[e];
    }
}

// ---- aggregation: one wave per node; packed CSR entries ((s<<2)|b) ----
// writes U (cols 128..255) and V (cols 256..383) hi/lo into A planes
__global__ void __launch_bounds__(256)
k_aggr(unsigned short* __restrict__ Ahi, unsigned short* __restrict__ Alo,
       const int* __restrict__ sp, const int* __restrict__ offs,
       const float* __restrict__ aw, const float* __restrict__ ab) {
    int lane = threadIdx.x & 63;
    int d = blockIdx.x * (blockDim.x >> 6) + (threadIdx.x >> 6);
    if (d >= NN) return;
    int k0 = lane * 2;

    // alpha = sigmoid(X[d] . aw + ab), hi+lo reconstruction
    unsigned int whi = *(const unsigned int*)(Ahi + (size_t)d * KTOT + k0);
    unsigned int wlo = *(const unsigned int*)(Alo + (size_t)d * KTOT + k0);
    float xa = bf2f((unsigned short)(whi & 0xffffu)) + bf2f((unsigned short)(wlo & 0xffffu));
    float xb = bf2f((unsigned short)(whi >> 16)) + bf2f((unsigned short)(wlo >> 16));
    float dot = xa * aw[k0] + xb * aw[k0 + 1];
#pragma unroll
    for (int m = 32; m > 0; m >>= 1) dot += __shfl_xor(dot, m, 64);
    float a = 1.0f / (1.0f + expf(-(dot + ab[0])));
    float oma = 1.0f - a;

    float u0 = 0.f, u1 = 0.f, v0 = 0.f, v1 = 0.f;
    int e0 = offs[d], e1 = offs[d + 1];
    int pk = (e0 < e1) ? sp[e0] : 0;
    for (int e = e0; e < e1; e++) {
        int pknext = (e + 1 < e1) ? sp[e + 1] : 0;   // independent prefetch
        int s = pk >> 2, b = pk & 3;
        unsigned int w = *(const unsigned int*)(Ahi + (size_t)s * KTOT + k0);
        float x0 = bf2f((unsigned short)(w & 0xffffu));
        float x1 = bf2f((unsigned short)(w >> 16));
        if (b == 1)      { u0 += x0; u1 += x1; }
        else if (b == 0) { v0 += x0; v1 += x1; }
        else             { u0 += a * x0; u1 += a * x1; v0 += oma * x0; v1 += oma * x1; }
        pk = pknext;
    }
    size_t ub = (size_t)d * KTOT + 128 + k0;
    size_t vb = (size_t)d * KTOT + 256 + k0;
    unsigned short h;
    h = f2bf(u0);
    float l0 = u0 - bf2f(h);
    unsigned short h1 = f2bf(u1);
    float l1 = u1 - bf2f(h1);
    *(unsigned int*)(Ahi + ub) = (unsigned int)h | ((unsigned int)h1 << 16);
    *(unsigned int*)(Alo + ub) = packbf(l0, l1);
    h = f2bf(v0); l0 = v0 - bf2f(h);
    h1 = f2bf(v1); l1 = v1 - bf2f(h1);
    *(unsigned int*)(Ahi + vb) = (unsigned int)h | ((unsigned int)h1 << 16);
    *(unsigned int*)(Alo + vb) = packbf(l0, l1);
}

// ---- MFMA GEMM: out = relu(A@Wcat + bias), A[N,384] bf16 hi/lo, 3-term f32 emulation.
// Writes result (hi/lo) in-place into A cols 0..127 (each wave touches only its own rows).
__global__ void __launch_bounds__(256)
k_mfma(unsigned short* __restrict__ Ahi, unsigned short* __restrict__ Alo,
       const unsigned short* __restrict__ WpHi, const unsigned short* __restrict__ WpLo,
       const float* __restrict__ bias) {
    int lane = threadIdx.x & 63;
    int wave = threadIdx.x >> 6;
    int r0 = blockIdx.x * 64 + wave * 16;
    if (r0 >= NN) return;

    int arow = r0 + (lane & 15);
    int kgrp = lane >> 4;
    const unsigned short* aHiP = Ahi + (size_t)arow * KTOT + kgrp * 8;
    const unsigned short* aLoP = Alo + (size_t)arow * KTOT + kgrp * 8;

    f32x4 acc[8];
#pragma unroll
    for (int i = 0; i < 8; i++) acc[i] = (f32x4){0.f, 0.f, 0.f, 0.f};

#pragma unroll
    for (int kt = 0; kt < 12; kt++) {
        short8 ahi = *(const short8*)(aHiP + kt * 32);
        short8 alo = *(const short8*)(aLoP + kt * 32);
#pragma unroll
        for (int ct = 0; ct < 8; ct++) {
            size_t wb = (((size_t)kt * 8 + ct) * 64 + lane) * 8;
            short8 bhi = *(const short8*)(WpHi + wb);
            short8 blo = *(const short8*)(WpLo + wb);
            acc[ct] = __builtin_amdgcn_mfma_f32_16x16x32_bf16(ahi, bhi, acc[ct], 0, 0, 0);
            acc[ct] = __builtin_amdgcn_mfma_f32_16x16x32_bf16(ahi, blo, acc[ct], 0, 0, 0);
            acc[ct] = __builtin_amdgcn_mfma_f32_16x16x32_bf16(alo, bhi, acc[ct], 0, 0, 0);
        }
    }

    // epilogue: C/D layout col=lane&15, row=(lane>>4)*4+reg  [m89-verified]
    int crow = r0 + (lane >> 4) * 4;
    int ccol = lane & 15;
#pragma unroll
    for (int ct = 0; ct < 8; ct++) {
        float bb = bias[ct * 16 + ccol];
#pragma unroll
        for (int r = 0; r < 4; r++) {
            float v = fmaxf(acc[ct][r] + bb, 0.f);
            unsigned short h = f2bf(v);
            unsigned short l = f2bf(v - bf2f(h));
            size_t off = (size_t)(crow + r) * KTOT + ct * 16 + ccol;
            Ahi[off] = h;
            Alo[off] = l;
        }
    }
}

// ---- classifier: out[N,8] f32, reads h2 (hi/lo) from A cols 0..127 ----
__global__ void __launch_bounds__(256)
k_cls(const unsigned short* __restrict__ Ahi, const unsigned short* __restrict__ Alo,
      const float* __restrict__ W, const float* __restrict__ b, float* __restrict__ out) {
    int lane = threadIdx.x & 63;
    int wid = blockIdx.x * (blockDim.x >> 6) + (threadIdx.x >> 6);
    if (wid >= NN) return;
    int cc = lane & 7;
    int kg = lane >> 3;
    const unsigned short* hH = Ahi + (size_t)wid * KTOT + kg * 16;
    const unsigned short* hL = Alo + (size_t)wid * KTOT + kg * 16;
    float s = 0.f;
#pragma unroll
    for (int j = 0; j < 16; j += 2) {
        unsigned int ph = *(const unsigned int*)(hH + j);
        unsigned int pl = *(const unsigned int*)(hL + j);
        float h0 = bf2f((unsigned short)(ph & 0xffffu)) + bf2f((unsigned short)(pl & 0xffffu));
        float h1 = bf2f((unsigned short)(ph >> 16)) + bf2f((unsigned short)(pl >> 16));
        s += h0 * W[(kg * 16 + j) * 8 + cc];
        s += h1 * W[(kg * 16 + j + 1) * 8 + cc];
    }
    s += __shfl_xor(s, 8, 64);
    s += __shfl_xor(s, 16, 64);
    s += __shfl_xor(s, 32, 64);
    if (lane < 8) out[(size_t)wid * 8 + cc] = s + b[cc];
}

extern "C" void kernel_launch(void* const* d_in, const int* in_sizes, int n_in,
                              void* d_out, int out_size, void* d_ws, size_t ws_size,
                              hipStream_t stream) {
    const float* x   = (const float*)d_in[0];
    const void* ei   = d_in[1];
    const void* y    = d_in[2];
    const void* mask = d_in[3];

    char* ws = (char*)d_ws;
    size_t cur_off = 0;
    auto alloc = [&](size_t bytes) {
        size_t o = cur_off;
        cur_off = (cur_off + bytes + 255) & ~(size_t)255;
        return o;
    };

    size_t oAhi = alloc((size_t)NN * KTOT * 2);   // 76.8 MB
    size_t oAlo = alloc((size_t)NN * KTOT * 2);   // 76.8 MB
    size_t oW1h = alloc(KTOT * D * 2);
    size_t oW1l = alloc(KTOT * D * 2);
    size_t oW2h = alloc(KTOT * D * 2);
    size_t oW2l = alloc(KTOT * D * 2);
    size_t oNT   = alloc(NN * 4);
    size_t oDEG  = alloc(NN * 4);
    size_t oOFFS = alloc((NN + 1) * 4);
    size_t oCUR  = alloc(NN * 4);
    size_t oBSUM = alloc(NBS * 4);
    size_t oBPRE = alloc(NBS * 4);
    size_t oSP   = alloc((size_t)NE * 4);
    size_t oDST  = alloc((size_t)NE * 4);
    size_t oSSRC = alloc((size_t)NE * 4);
    size_t oFLG  = alloc(256);

    unsigned short* Ahi = (unsigned short*)(ws + oAhi);
    unsigned short* Alo = (unsigned short*)(ws + oAlo);
    unsigned short* W1h = (unsigned short*)(ws + oW1h);
    unsigned short* W1l = (unsigned short*)(ws + oW1l);
    unsigned short* W2h = (unsigned short*)(ws + oW2h);
    unsigned short* W2l = (unsigned short*)(ws + oW2l);
    int* NT   = (int*)(ws + oNT);
    int* DEG  = (int*)(ws + oDEG);
    int* OFFS = (int*)(ws + oOFFS);
    int* CURB = (int*)(ws + oCUR);
    int* BSUM = (int*)(ws + oBSUM);
    int* BPRE = (int*)(ws + oBPRE);
    int* SP   = (int*)(ws + oSP);
    int* DST  = (int*)(ws + oDST);
    int* SSRC = (int*)(ws + oSSRC);
    int* FLG  = (int*)(ws + oFLG);

    hipMemsetAsync(DEG, 0, NN * sizeof(int), stream);
    hipMemsetAsync(CURB, 0, NN * sizeof(int), stream);

    k_detect<<<1, 64, 0, stream>>>((const unsigned int*)ei, (const unsigned int*)y,
                                   (const unsigned int*)mask, FLG);
    k_prep<<<(NN + 255) / 256, 256, 0, stream>>>(FLG, y, mask, NT);
    k_conv_e<<<(NE + 255) / 256, 256, 0, stream>>>(FLG, ei, NT, SP, DST);
    k_convx<<<NN * D / 4 / 256, 256, 0, stream>>>(x, Ahi, Alo);
    k_wprep<<<(KTOT * D + 255) / 256, 256, 0, stream>>>(
        (const float*)d_in[8], (const float*)d_in[4], (const float*)d_in[5], W1h, W1l);
    k_wprep<<<(KTOT * D + 255) / 256, 256, 0, stream>>>(
        (const float*)d_in[14], (const float*)d_in[10], (const float*)d_in[11], W2h, W2l);

    k_hist<<<2048, 256, 0, stream>>>(DST, DEG);
    k_scan_a<<<NBS, 256, 0, stream>>>(DEG, BSUM);
    k_scan_b<<<1, 128, 0, stream>>>(BSUM, BPRE, OFFS);
    k_scan_c<<<NBS, 256, 0, stream>>>(DEG, BPRE, OFFS);
    k_place<<<2048, 256, 0, stream>>>(SP, DST, OFFS, CURB, SSRC);

    // layer 1
    k_aggr<<<NN / 4, 256, 0, stream>>>(Ahi, Alo, SSRC, OFFS,
        (const float*)d_in[6], (const float*)d_in[7]);
    k_mfma<<<(NN + 63) / 64, 256, 0, stream>>>(Ahi, Alo, W1h, W1l, (const float*)d_in[9]);
    // layer 2 (H now lives in A cols 0..127)
    k_aggr<<<NN / 4, 256, 0, stream>>>(Ahi, Alo, SSRC, OFFS,
        (const float*)d_in[12], (const float*)d_in[13]);
    k_mfma<<<(NN + 63) / 64, 256, 0, stream>>>(Ahi, Alo, W2h, W2l, (const float*)d_in[15]);

    k_cls<<<NN / 4, 256, 0, stream>>>(Ahi, Alo, (const float*)d_in[16],
                                      (const float*)d_in[17], (float*)d_out);
}

// Round 6
// 555.343 us; speedup vs baseline: 2.6975x; 1.3405x over previous
//
#include <hip/hip_runtime.h>
#include <hip/hip_bf16.h>
#include <cmath>

#define DEV static __device__ __forceinline__

constexpr int NN = 100000;
constexpr int NN_PAD = 100352;     // 784 * 128, pad rows never reach d_out
constexpr int NE = 1600000;
constexpr int D  = 128;
constexpr int KTOT = 384;          // [X | U | V]
constexpr int SCHUNK = 1024;
constexpr int NBS = (NN + SCHUNK - 1) / SCHUNK;   // 98

typedef __attribute__((ext_vector_type(8))) short short8;
typedef __attribute__((ext_vector_type(4))) float f32x4;

DEV float bf2f(unsigned short u) {
    unsigned int t = ((unsigned int)u) << 16;
    return __builtin_bit_cast(float, t);
}
DEV unsigned short f2bf(float f) {
    unsigned int u = __builtin_bit_cast(unsigned int, f);
    u += 0x7fffu + ((u >> 16) & 1u);   // RNE
    return (unsigned short)(u >> 16);
}
DEV unsigned int packbf(float a, float b) {
    return (unsigned int)f2bf(a) | ((unsigned int)f2bf(b) << 16);
}

// ---- int-width detection (proven) ----
__global__ void k_detect(const unsigned int* __restrict__ ew,
                         const unsigned int* __restrict__ yw,
                         const unsigned int* __restrict__ mw,
                         int* __restrict__ flags) {
    if (threadIdx.x != 0 || blockIdx.x != 0) return;
    int nz = 0;
    for (int i = 0; i < 64; i++) if (ew[2 * i + 1] != 0u) nz++;
    flags[1] = (nz < 8) ? 1 : 0;
    nz = 0;
    for (int i = 0; i < 64; i++) if (yw[2 * i + 1] != 0u) nz++;
    flags[2] = (nz < 8) ? 1 : 0;
    int big = 0; nz = 0;
    for (int i = 0; i < 64; i++) if (mw[i] > 1u) big++;
    for (int i = 0; i < 64; i++) if (mw[2 * i + 1] != 0u) nz++;
    flags[3] = big > 8 ? 2 : (nz < 8 ? 1 : 0);
}

__global__ void k_prep(const int* __restrict__ flg, const void* __restrict__ y,
                       const void* __restrict__ mask, int* __restrict__ nt) {
    int i = blockIdx.x * blockDim.x + threadIdx.x;
    if (i >= NN) return;
    int yv = flg[2] ? (int)((const long long*)y)[i] : ((const int*)y)[i];
    int mm = flg[3] == 2 ? (int)((const unsigned char*)mask)[i]
           : flg[3] == 1 ? (int)((const long long*)mask)[i]
           : ((const int*)mask)[i];
    nt[i] = mm ? yv : 2;
}

// edges -> packed src ((s<<2)|nt[s]), dst, and degree histogram (fused)
__global__ void k_conv_e(const int* __restrict__ flg, const void* __restrict__ ei,
                         const int* __restrict__ nt,
                         int* __restrict__ SP, int* __restrict__ DST,
                         int* __restrict__ deg) {
    int e = blockIdx.x * blockDim.x + threadIdx.x;
    if (e >= NE) return;
    int s, d;
    if (flg[1]) {
        const long long* p = (const long long*)ei;
        s = (int)p[e]; d = (int)p[NE + e];
    } else {
        const int* p = (const int*)ei;
        s = p[e]; d = p[NE + e];
    }
    SP[e] = (s << 2) | nt[s];
    DST[e] = d;
    atomicAdd(&deg[d], 1);
}

// x (f32) -> Ahi cols 0..127 (stride 384) + XLO (stride 128)
__global__ void k_convx(const float* __restrict__ x,
                        unsigned short* __restrict__ Ahi, unsigned short* __restrict__ XLO) {
    long t = blockIdx.x * (long)blockDim.x + threadIdx.x;
    long g = t * 4;
    if (g >= (long)NN * D) return;
    int n = (int)(g >> 7);
    int k = (int)(g & 127);
    float4 v = *(const float4*)(x + g);
    float vv[4] = {v.x, v.y, v.z, v.w};
    ushort4 hi, lo;
    unsigned short* hp = (unsigned short*)&hi;
    unsigned short* lp = (unsigned short*)&lo;
#pragma unroll
    for (int j = 0; j < 4; j++) {
        unsigned short h = f2bf(vv[j]);
        hp[j] = h;
        lp[j] = f2bf(vv[j] - bf2f(h));
    }
    *(ushort4*)(Ahi + (size_t)n * KTOT + k) = hi;
    *(ushort4*)(XLO + (size_t)n * D + k) = lo;
}

// weights -> B-fragment-ordered hi/lo planes (k: 0..127 Wself, 128..255 Wfr, 256..383 Wbe)
__global__ void k_wprep(const float* __restrict__ Wsf, const float* __restrict__ Wfr,
                        const float* __restrict__ Wbe,
                        unsigned short* __restrict__ WpHi, unsigned short* __restrict__ WpLo) {
    int t = blockIdx.x * blockDim.x + threadIdx.x;
    if (t >= KTOT * D) return;
    int k = t >> 7;
    int c = t & 127;
    float w = k < 128 ? Wsf[k * 128 + c]
            : k < 256 ? Wfr[(k - 128) * 128 + c]
            : Wbe[(k - 256) * 128 + c];
    unsigned short hi = f2bf(w);
    unsigned short lo = f2bf(w - bf2f(hi));
    int kt = k >> 5, kin = k & 31;
    int grp = kin >> 3, j = kin & 7;
    int ct = c >> 4, cl = c & 15;
    size_t idx = (((size_t)kt * 8 + ct) * 64 + ((grp << 4) | cl)) * 8 + j;
    WpHi[idx] = hi;
    WpLo[idx] = lo;
}

// ---- CSR scans ----
__global__ void k_scan_a(const int* __restrict__ deg, int* __restrict__ bsum) {
    __shared__ int sh[256];
    int b = blockIdx.x, t = threadIdx.x;
    int base = b * SCHUNK + t * 4;
    int s = 0;
#pragma unroll
    for (int j = 0; j < 4; j++) { int i = base + j; if (i < NN) s += deg[i]; }
    sh[t] = s; __syncthreads();
    for (int d = 128; d > 0; d >>= 1) {
        if (t < d) sh[t] += sh[t + d];
        __syncthreads();
    }
    if (t == 0) bsum[b] = sh[0];
}

__global__ void k_scan_b(const int* __restrict__ bsum, int* __restrict__ bpre,
                         int* __restrict__ offs) {
    __shared__ int sh[128];
    int t = threadIdx.x;
    int v = (t < NBS) ? bsum[t] : 0;
    int incl = v; sh[t] = incl; __syncthreads();
    for (int d = 1; d < 128; d <<= 1) {
        int add = (t >= d) ? sh[t - d] : 0;
        __syncthreads();
        incl += add; sh[t] = incl;
        __syncthreads();
    }
    if (t < NBS) bpre[t] = incl - v;
    if (t == 0) offs[NN] = NE;
}

__global__ void k_scan_c(const int* __restrict__ deg, const int* __restrict__ bpre,
                         int* __restrict__ offs) {
    __shared__ int sh[256];
    int b = blockIdx.x, t = threadIdx.x;
    int base = b * SCHUNK + t * 4;
    int v[4];
#pragma unroll
    for (int j = 0; j < 4; j++) { int i = base + j; v[j] = (i < NN) ? deg[i] : 0; }
    int tsum = v[0] + v[1] + v[2] + v[3];
    int incl = tsum; sh[t] = incl; __syncthreads();
    for (int d = 1; d < 256; d <<= 1) {
        int add = (t >= d) ? sh[t - d] : 0;
        __syncthreads();
        incl += add; sh[t] = incl;
        __syncthreads();
    }
    int ex = (incl - tsum) + bpre[b];
#pragma unroll
    for (int j = 0; j < 4; j++) {
        int i = base + j;
        if (i < NN) { offs[i] = ex; ex += v[j]; }
    }
}

__global__ void k_place(const int* __restrict__ SP, const int* __restrict__ DST,
                        const int* __restrict__ offs, int* __restrict__ cur,
                        int* __restrict__ ssrc) {
    for (int e = blockIdx.x * blockDim.x + threadIdx.x; e < NE; e += gridDim.x * blockDim.x) {
        int d = DST[e];
        int p = offs[d] + atomicAdd(&cur[d], 1);
        ssrc[p] = SP[e];
    }
}

// ---- aggregation: one wave per node, 8-deep gather ILP, branchless coefs ----
// writes U (cols 128..255) and V (cols 256..383) hi into Ahi
__global__ void __launch_bounds__(256)
k_aggr(unsigned short* __restrict__ Ahi, const unsigned short* __restrict__ XLO,
       const int* __restrict__ sp, const int* __restrict__ offs,
       const float* __restrict__ aw, const float* __restrict__ ab) {
    int lane = threadIdx.x & 63;
    int d = blockIdx.x * (blockDim.x >> 6) + (threadIdx.x >> 6);
    if (d >= NN) return;
    int k0 = lane * 2;

    // alpha = sigmoid(X[d] . aw + ab)  (hi from Ahi, lo from XLO)
    unsigned int whi = *(const unsigned int*)(Ahi + (size_t)d * KTOT + k0);
    unsigned int wlo = *(const unsigned int*)(XLO + (size_t)d * D + k0);
    float xa = bf2f((unsigned short)(whi & 0xffffu)) + bf2f((unsigned short)(wlo & 0xffffu));
    float xb = bf2f((unsigned short)(whi >> 16)) + bf2f((unsigned short)(wlo >> 16));
    float dot = xa * aw[k0] + xb * aw[k0 + 1];
#pragma unroll
    for (int m = 32; m > 0; m >>= 1) dot += __shfl_xor(dot, m, 64);
    float a = 1.0f / (1.0f + expf(-(dot + ab[0])));
    float oma = 1.0f - a;

    float u0 = 0.f, u1 = 0.f, v0 = 0.f, v1 = 0.f;
    int e0 = offs[d];
    int n = offs[d + 1] - e0;
    const int* spp = sp + e0;
    for (int base = 0; base < n; base += 8) {
        float xs0[8], xs1[8], cu[8], cv[8];
#pragma unroll
        for (int j = 0; j < 8; j++) {
            int idx = base + j;
            int cidx = idx < n ? idx : n - 1;
            int pk = spp[cidx];                  // wave-uniform -> scalar load
            int b = pk & 3;
            int s = pk >> 2;
            float cuj = (b == 1) ? 1.f : (b == 0 ? 0.f : a);
            float cvj = (b == 0) ? 1.f : (b == 1 ? 0.f : oma);
            bool valid = idx < n;
            cu[j] = valid ? cuj : 0.f;
            cv[j] = valid ? cvj : 0.f;
            unsigned int w = *(const unsigned int*)(Ahi + (size_t)s * KTOT + k0);
            xs0[j] = bf2f((unsigned short)(w & 0xffffu));
            xs1[j] = bf2f((unsigned short)(w >> 16));
        }
#pragma unroll
        for (int j = 0; j < 8; j++) {
            u0 += cu[j] * xs0[j]; u1 += cu[j] * xs1[j];
            v0 += cv[j] * xs0[j]; v1 += cv[j] * xs1[j];
        }
    }
    *(unsigned int*)(Ahi + (size_t)d * KTOT + 128 + k0) = packbf(u0, u1);
    *(unsigned int*)(Ahi + (size_t)d * KTOT + 256 + k0) = packbf(v0, v1);
}

// ---- MFMA GEMM: relu(A@Wcat + bias); 32 rows/wave; A-lo only for X k-tiles ----
__global__ void __launch_bounds__(256)
k_mfma(unsigned short* __restrict__ Ahi, unsigned short* __restrict__ XLO,
       const unsigned short* __restrict__ WpHi, const unsigned short* __restrict__ WpLo,
       const float* __restrict__ bias) {
    int lane = threadIdx.x & 63;
    int wave = threadIdx.x >> 6;
    int r0 = blockIdx.x * 128 + wave * 32;

    int mrow = lane & 15, kgrp = lane >> 4;
    const unsigned short* aHi0 = Ahi + (size_t)(r0 + mrow) * KTOT + kgrp * 8;
    const unsigned short* aHi1 = aHi0 + (size_t)16 * KTOT;
    const unsigned short* aLo0 = XLO + (size_t)(r0 + mrow) * D + kgrp * 8;
    const unsigned short* aLo1 = aLo0 + (size_t)16 * D;

    f32x4 acc[2][8];
#pragma unroll
    for (int m = 0; m < 2; m++)
#pragma unroll
        for (int i = 0; i < 8; i++) acc[m][i] = (f32x4){0.f, 0.f, 0.f, 0.f};

#pragma unroll
    for (int kt = 0; kt < 12; kt++) {
        short8 a0 = *(const short8*)(aHi0 + kt * 32);
        short8 a1 = *(const short8*)(aHi1 + kt * 32);
        short8 l0, l1;
        if (kt < 4) {
            l0 = *(const short8*)(aLo0 + kt * 32);
            l1 = *(const short8*)(aLo1 + kt * 32);
        }
#pragma unroll
        for (int ct = 0; ct < 8; ct++) {
            size_t wb = (((size_t)kt * 8 + ct) * 64 + lane) * 8;
            short8 bh = *(const short8*)(WpHi + wb);
            short8 bl = *(const short8*)(WpLo + wb);
            acc[0][ct] = __builtin_amdgcn_mfma_f32_16x16x32_bf16(a0, bh, acc[0][ct], 0, 0, 0);
            acc[0][ct] = __builtin_amdgcn_mfma_f32_16x16x32_bf16(a0, bl, acc[0][ct], 0, 0, 0);
            acc[1][ct] = __builtin_amdgcn_mfma_f32_16x16x32_bf16(a1, bh, acc[1][ct], 0, 0, 0);
            acc[1][ct] = __builtin_amdgcn_mfma_f32_16x16x32_bf16(a1, bl, acc[1][ct], 0, 0, 0);
            if (kt < 4) {
                acc[0][ct] = __builtin_amdgcn_mfma_f32_16x16x32_bf16(l0, bh, acc[0][ct], 0, 0, 0);
                acc[1][ct] = __builtin_amdgcn_mfma_f32_16x16x32_bf16(l1, bh, acc[1][ct], 0, 0, 0);
            }
        }
    }

    // epilogue: C/D layout col=lane&15, row=(lane>>4)*4+reg [m89-verified]
    int ccol = lane & 15;
#pragma unroll
    for (int m = 0; m < 2; m++) {
        int crow = r0 + m * 16 + (lane >> 4) * 4;
#pragma unroll
        for (int ct = 0; ct < 8; ct++) {
            float bb = bias[ct * 16 + ccol];
#pragma unroll
            for (int r = 0; r < 4; r++) {
                float v = fmaxf(acc[m][ct][r] + bb, 0.f);
                unsigned short h = f2bf(v);
                unsigned short l = f2bf(v - bf2f(h));
                Ahi[(size_t)(crow + r) * KTOT + ct * 16 + ccol] = h;
                XLO[(size_t)(crow + r) * D + ct * 16 + ccol] = l;
            }
        }
    }
}

// ---- classifier: out[N,8] f32 from H (Ahi cols 0..127 + XLO) ----
__global__ void __launch_bounds__(256)
k_cls(const unsigned short* __restrict__ Ahi, const unsigned short* __restrict__ XLO,
      const float* __restrict__ W, const float* __restrict__ b, float* __restrict__ out) {
    int lane = threadIdx.x & 63;
    int wid = blockIdx.x * (blockDim.x >> 6) + (threadIdx.x >> 6);
    if (wid >= NN) return;
    int cc = lane & 7;
    int kg = lane >> 3;
    const unsigned short* hH = Ahi + (size_t)wid * KTOT + kg * 16;
    const unsigned short* hL = XLO + (size_t)wid * D + kg * 16;
    float s = 0.f;
#pragma unroll
    for (int j = 0; j < 16; j += 2) {
        unsigned int ph = *(const unsigned int*)(hH + j);
        unsigned int pl = *(const unsigned int*)(hL + j);
        float h0 = bf2f((unsigned short)(ph & 0xffffu)) + bf2f((unsigned short)(pl & 0xffffu));
        float h1 = bf2f((unsigned short)(ph >> 16)) + bf2f((unsigned short)(pl >> 16));
        s += h0 * W[(kg * 16 + j) * 8 + cc];
        s += h1 * W[(kg * 16 + j + 1) * 8 + cc];
    }
    s += __shfl_xor(s, 8, 64);
    s += __shfl_xor(s, 16, 64);
    s += __shfl_xor(s, 32, 64);
    if (lane < 8) out[(size_t)wid * 8 + cc] = s + b[cc];
}

extern "C" void kernel_launch(void* const* d_in, const int* in_sizes, int n_in,
                              void* d_out, int out_size, void* d_ws, size_t ws_size,
                              hipStream_t stream) {
    const float* x   = (const float*)d_in[0];
    const void* ei   = d_in[1];
    const void* y    = d_in[2];
    const void* mask = d_in[3];

    char* ws = (char*)d_ws;
    size_t cur_off = 0;
    auto alloc = [&](size_t bytes) {
        size_t o = cur_off;
        cur_off = (cur_off + bytes + 255) & ~(size_t)255;
        return o;
    };

    size_t oAhi = alloc((size_t)NN_PAD * KTOT * 2);   // 77.1 MB
    size_t oXLO = alloc((size_t)NN_PAD * D * 2);      // 25.7 MB
    size_t oW1h = alloc(KTOT * D * 2);
    size_t oW1l = alloc(KTOT * D * 2);
    size_t oW2h = alloc(KTOT * D * 2);
    size_t oW2l = alloc(KTOT * D * 2);
    size_t oNT   = alloc(NN * 4);
    size_t oDEG  = alloc(NN * 4);
    size_t oOFFS = alloc((NN + 1) * 4);
    size_t oCUR  = alloc(NN * 4);
    size_t oBSUM = alloc(NBS * 4);
    size_t oBPRE = alloc(NBS * 4);
    size_t oSP   = alloc((size_t)NE * 4);
    size_t oDST  = alloc((size_t)NE * 4);
    size_t oSSRC = alloc((size_t)NE * 4);
    size_t oFLG  = alloc(256);

    unsigned short* Ahi = (unsigned short*)(ws + oAhi);
    unsigned short* XLO = (unsigned short*)(ws + oXLO);
    unsigned short* W1h = (unsigned short*)(ws + oW1h);
    unsigned short* W1l = (unsigned short*)(ws + oW1l);
    unsigned short* W2h = (unsigned short*)(ws + oW2h);
    unsigned short* W2l = (unsigned short*)(ws + oW2l);
    int* NT   = (int*)(ws + oNT);
    int* DEG  = (int*)(ws + oDEG);
    int* OFFS = (int*)(ws + oOFFS);
    int* CURB = (int*)(ws + oCUR);
    int* BSUM = (int*)(ws + oBSUM);
    int* BPRE = (int*)(ws + oBPRE);
    int* SP   = (int*)(ws + oSP);
    int* DST  = (int*)(ws + oDST);
    int* SSRC = (int*)(ws + oSSRC);
    int* FLG  = (int*)(ws + oFLG);

    hipMemsetAsync(DEG, 0, NN * sizeof(int), stream);
    hipMemsetAsync(CURB, 0, NN * sizeof(int), stream);

    k_detect<<<1, 64, 0, stream>>>((const unsigned int*)ei, (const unsigned int*)y,
                                   (const unsigned int*)mask, FLG);
    k_prep<<<(NN + 255) / 256, 256, 0, stream>>>(FLG, y, mask, NT);
    k_conv_e<<<(NE + 255) / 256, 256, 0, stream>>>(FLG, ei, NT, SP, DST, DEG);
    k_convx<<<NN * D / 4 / 256, 256, 0, stream>>>(x, Ahi, XLO);
    k_wprep<<<(KTOT * D + 255) / 256, 256, 0, stream>>>(
        (const float*)d_in[8], (const float*)d_in[4], (const float*)d_in[5], W1h, W1l);
    k_wprep<<<(KTOT * D + 255) / 256, 256, 0, stream>>>(
        (const float*)d_in[14], (const float*)d_in[10], (const float*)d_in[11], W2h, W2l);

    k_scan_a<<<NBS, 256, 0, stream>>>(DEG, BSUM);
    k_scan_b<<<1, 128, 0, stream>>>(BSUM, BPRE, OFFS);
    k_scan_c<<<NBS, 256, 0, stream>>>(DEG, BPRE, OFFS);
    k_place<<<2048, 256, 0, stream>>>(SP, DST, OFFS, CURB, SSRC);

    // layer 1
    k_aggr<<<NN / 4, 256, 0, stream>>>(Ahi, XLO, SSRC, OFFS,
        (const float*)d_in[6], (const float*)d_in[7]);
    k_mfma<<<NN_PAD / 128, 256, 0, stream>>>(Ahi, XLO, W1h, W1l, (const float*)d_in[9]);
    // layer 2 (H in Ahi cols 0..127 + XLO)
    k_aggr<<<NN / 4, 256, 0, stream>>>(Ahi, XLO, SSRC, OFFS,
        (const float*)d_in[12], (const float*)d_in[13]);
    k_mfma<<<NN_PAD / 128, 256, 0, stream>>>(Ahi, XLO, W2h, W2l, (const float*)d_in[15]);

    k_cls<<<NN / 4, 256, 0, stream>>>(Ahi, XLO, (const float*)d_in[16],
                                      (const float*)d_in[17], (float*)d_out);
}

// Round 7
// 544.336 us; speedup vs baseline: 2.7520x; 1.0202x over previous
//
#include <hip/hip_runtime.h>
#include <hip/hip_bf16.h>
#include <cmath>

#define DEV static __device__ __forceinline__

constexpr int NN = 100000;
constexpr int NN_PAD = 100352;     // 392 * 256, pad rows never reach d_out
constexpr int NE = 1600000;
constexpr int D  = 128;
constexpr int KTOT = 384;          // [X | U | V]
constexpr int SCHUNK = 1024;
constexpr int NBS = (NN + SCHUNK - 1) / SCHUNK;   // 98

typedef __attribute__((ext_vector_type(8))) short short8;
typedef __attribute__((ext_vector_type(4))) float f32x4;

DEV float bf2f(unsigned short u) {
    unsigned int t = ((unsigned int)u) << 16;
    return __builtin_bit_cast(float, t);
}
DEV unsigned short f2bf(float f) {
    unsigned int u = __builtin_bit_cast(unsigned int, f);
    u += 0x7fffu + ((u >> 16) & 1u);   // RNE
    return (unsigned short)(u >> 16);
}
DEV unsigned int packbf(float a, float b) {
    return (unsigned int)f2bf(a) | ((unsigned int)f2bf(b) << 16);
}

// ---- int-width detection (proven) ----
__global__ void k_detect(const unsigned int* __restrict__ ew,
                         const unsigned int* __restrict__ yw,
                         const unsigned int* __restrict__ mw,
                         int* __restrict__ flags) {
    if (threadIdx.x != 0 || blockIdx.x != 0) return;
    int nz = 0;
    for (int i = 0; i < 64; i++) if (ew[2 * i + 1] != 0u) nz++;
    flags[1] = (nz < 8) ? 1 : 0;
    nz = 0;
    for (int i = 0; i < 64; i++) if (yw[2 * i + 1] != 0u) nz++;
    flags[2] = (nz < 8) ? 1 : 0;
    int big = 0; nz = 0;
    for (int i = 0; i < 64; i++) if (mw[i] > 1u) big++;
    for (int i = 0; i < 64; i++) if (mw[2 * i + 1] != 0u) nz++;
    flags[3] = big > 8 ? 2 : (nz < 8 ? 1 : 0);
}

__global__ void k_prep(const int* __restrict__ flg, const void* __restrict__ y,
                       const void* __restrict__ mask, int* __restrict__ nt) {
    int i = blockIdx.x * blockDim.x + threadIdx.x;
    if (i >= NN) return;
    int yv = flg[2] ? (int)((const long long*)y)[i] : ((const int*)y)[i];
    int mm = flg[3] == 2 ? (int)((const unsigned char*)mask)[i]
           : flg[3] == 1 ? (int)((const long long*)mask)[i]
           : ((const int*)mask)[i];
    nt[i] = mm ? yv : 2;
}

// edges -> packed src ((s<<2)|nt[s]), dst, degree histogram + per-edge rank (fused)
__global__ void k_conv_e(const int* __restrict__ flg, const void* __restrict__ ei,
                         const int* __restrict__ nt,
                         int* __restrict__ SP, int* __restrict__ DST,
                         int* __restrict__ deg, int* __restrict__ rnk) {
    int e = blockIdx.x * blockDim.x + threadIdx.x;
    if (e >= NE) return;
    int s, d;
    if (flg[1]) {
        const long long* p = (const long long*)ei;
        s = (int)p[e]; d = (int)p[NE + e];
    } else {
        const int* p = (const int*)ei;
        s = p[e]; d = p[NE + e];
    }
    SP[e] = (s << 2) | nt[s];
    DST[e] = d;
    rnk[e] = atomicAdd(&deg[d], 1);
}

// x (f32) -> Ahi cols 0..127 (stride 384) + XLO (stride 128)
__global__ void k_convx(const float* __restrict__ x,
                        unsigned short* __restrict__ Ahi, unsigned short* __restrict__ XLO) {
    long t = blockIdx.x * (long)blockDim.x + threadIdx.x;
    long g = t * 4;
    if (g >= (long)NN * D) return;
    int n = (int)(g >> 7);
    int k = (int)(g & 127);
    float4 v = *(const float4*)(x + g);
    float vv[4] = {v.x, v.y, v.z, v.w};
    ushort4 hi, lo;
    unsigned short* hp = (unsigned short*)&hi;
    unsigned short* lp = (unsigned short*)&lo;
#pragma unroll
    for (int j = 0; j < 4; j++) {
        unsigned short h = f2bf(vv[j]);
        hp[j] = h;
        lp[j] = f2bf(vv[j] - bf2f(h));
    }
    *(ushort4*)(Ahi + (size_t)n * KTOT + k) = hi;
    *(ushort4*)(XLO + (size_t)n * D + k) = lo;
}

// weights -> B-fragment-ordered hi/lo planes (k: 0..127 Wself, 128..255 Wfr, 256..383 Wbe)
__global__ void k_wprep(const float* __restrict__ Wsf, const float* __restrict__ Wfr,
                        const float* __restrict__ Wbe,
                        unsigned short* __restrict__ WpHi, unsigned short* __restrict__ WpLo) {
    int t = blockIdx.x * blockDim.x + threadIdx.x;
    if (t >= KTOT * D) return;
    int k = t >> 7;
    int c = t & 127;
    float w = k < 128 ? Wsf[k * 128 + c]
            : k < 256 ? Wfr[(k - 128) * 128 + c]
            : Wbe[(k - 256) * 128 + c];
    unsigned short hi = f2bf(w);
    unsigned short lo = f2bf(w - bf2f(hi));
    int kt = k >> 5, kin = k & 31;
    int grp = kin >> 3, j = kin & 7;
    int ct = c >> 4, cl = c & 15;
    size_t idx = (((size_t)kt * 8 + ct) * 64 + ((grp << 4) | cl)) * 8 + j;
    WpHi[idx] = hi;
    WpLo[idx] = lo;
}

// ---- CSR scans ----
__global__ void k_scan_a(const int* __restrict__ deg, int* __restrict__ bsum) {
    __shared__ int sh[256];
    int b = blockIdx.x, t = threadIdx.x;
    int base = b * SCHUNK + t * 4;
    int s = 0;
#pragma unroll
    for (int j = 0; j < 4; j++) { int i = base + j; if (i < NN) s += deg[i]; }
    sh[t] = s; __syncthreads();
    for (int d = 128; d > 0; d >>= 1) {
        if (t < d) sh[t] += sh[t + d];
        __syncthreads();
    }
    if (t == 0) bsum[b] = sh[0];
}

__global__ void k_scan_b(const int* __restrict__ bsum, int* __restrict__ bpre,
                         int* __restrict__ offs) {
    __shared__ int sh[128];
    int t = threadIdx.x;
    int v = (t < NBS) ? bsum[t] : 0;
    int incl = v; sh[t] = incl; __syncthreads();
    for (int d = 1; d < 128; d <<= 1) {
        int add = (t >= d) ? sh[t - d] : 0;
        __syncthreads();
        incl += add; sh[t] = incl;
        __syncthreads();
    }
    if (t < NBS) bpre[t] = incl - v;
    if (t == 0) offs[NN] = NE;
}

__global__ void k_scan_c(const int* __restrict__ deg, const int* __restrict__ bpre,
                         int* __restrict__ offs) {
    __shared__ int sh[256];
    int b = blockIdx.x, t = threadIdx.x;
    int base = b * SCHUNK + t * 4;
    int v[4];
#pragma unroll
    for (int j = 0; j < 4; j++) { int i = base + j; v[j] = (i < NN) ? deg[i] : 0; }
    int tsum = v[0] + v[1] + v[2] + v[3];
    int incl = tsum; sh[t] = incl; __syncthreads();
    for (int d = 1; d < 256; d <<= 1) {
        int add = (t >= d) ? sh[t - d] : 0;
        __syncthreads();
        incl += add; sh[t] = incl;
        __syncthreads();
    }
    int ex = (incl - tsum) + bpre[b];
#pragma unroll
    for (int j = 0; j < 4; j++) {
        int i = base + j;
        if (i < NN) { offs[i] = ex; ex += v[j]; }
    }
}

// pure permutation scatter (no atomics): slot = offs[dst] + rank
__global__ void k_place(const int* __restrict__ SP, const int* __restrict__ DST,
                        const int* __restrict__ RNK, const int* __restrict__ offs,
                        int* __restrict__ ssrc) {
    for (int e = blockIdx.x * blockDim.x + threadIdx.x; e < NE; e += gridDim.x * blockDim.x) {
        int d = DST[e];
        int slot = offs[d] + RNK[e];
        __builtin_nontemporal_store(SP[e], &ssrc[slot]);
    }
}

// ---- aggregation: one wave per node, 16-deep gather ILP, branchless coefs ----
// writes U (cols 128..255) and V (cols 256..383) hi into Ahi
__global__ void __launch_bounds__(256)
k_aggr(unsigned short* __restrict__ Ahi, const unsigned short* __restrict__ XLO,
       const int* __restrict__ sp, const int* __restrict__ offs,
       const float* __restrict__ aw, const float* __restrict__ ab) {
    int lane = threadIdx.x & 63;
    int d = blockIdx.x * (blockDim.x >> 6) + (threadIdx.x >> 6);
    if (d >= NN) return;
    int k0 = lane * 2;

    // alpha = sigmoid(X[d] . aw + ab)  (hi from Ahi, lo from XLO)
    unsigned int whi = *(const unsigned int*)(Ahi + (size_t)d * KTOT + k0);
    unsigned int wlo = *(const unsigned int*)(XLO + (size_t)d * D + k0);
    float xa = bf2f((unsigned short)(whi & 0xffffu)) + bf2f((unsigned short)(wlo & 0xffffu));
    float xb = bf2f((unsigned short)(whi >> 16)) + bf2f((unsigned short)(wlo >> 16));
    float dot = xa * aw[k0] + xb * aw[k0 + 1];
#pragma unroll
    for (int m = 32; m > 0; m >>= 1) dot += __shfl_xor(dot, m, 64);
    float a = 1.0f / (1.0f + expf(-(dot + ab[0])));
    float oma = 1.0f - a;

    float u0 = 0.f, u1 = 0.f, v0 = 0.f, v1 = 0.f;
    int e0 = offs[d];
    int n = offs[d + 1] - e0;
    const int* spp = sp + e0;
    for (int base = 0; base < n; base += 16) {
        float xs0[16], xs1[16], cu[16], cv[16];
#pragma unroll
        for (int j = 0; j < 16; j++) {
            int idx = base + j;
            int cidx = idx < n ? idx : n - 1;
            int pk = spp[cidx];                  // wave-uniform -> scalar load
            int b = pk & 3;
            int s = pk >> 2;
            float cuj = (b == 1) ? 1.f : (b == 0 ? 0.f : a);
            float cvj = (b == 0) ? 1.f : (b == 1 ? 0.f : oma);
            bool valid = idx < n;
            cu[j] = valid ? cuj : 0.f;
            cv[j] = valid ? cvj : 0.f;
            unsigned int w = *(const unsigned int*)(Ahi + (size_t)s * KTOT + k0);
            xs0[j] = bf2f((unsigned short)(w & 0xffffu));
            xs1[j] = bf2f((unsigned short)(w >> 16));
        }
#pragma unroll
        for (int j = 0; j < 16; j++) {
            u0 += cu[j] * xs0[j]; u1 += cu[j] * xs1[j];
            v0 += cv[j] * xs0[j]; v1 += cv[j] * xs1[j];
        }
    }
    *(unsigned int*)(Ahi + (size_t)d * KTOT + 128 + k0) = packbf(u0, u1);
    *(unsigned int*)(Ahi + (size_t)d * KTOT + 256 + k0) = packbf(v0, v1);
}

// ---- MFMA GEMM: relu(A@Wcat + bias); 64 rows/wave; A-lo only for X k-tiles ----
__global__ void __launch_bounds__(256)
k_mfma(unsigned short* __restrict__ Ahi, unsigned short* __restrict__ XLO,
       const unsigned short* __restrict__ WpHi, const unsigned short* __restrict__ WpLo,
       const float* __restrict__ bias) {
    int lane = threadIdx.x & 63;
    int wave = threadIdx.x >> 6;
    int r0 = blockIdx.x * 256 + wave * 64;

    int mrow = lane & 15, kgrp = lane >> 4;
    const unsigned short* aHiB = Ahi + (size_t)(r0 + mrow) * KTOT + kgrp * 8;
    const unsigned short* aLoB = XLO + (size_t)(r0 + mrow) * D + kgrp * 8;

    f32x4 acc[4][8];
#pragma unroll
    for (int m = 0; m < 4; m++)
#pragma unroll
        for (int i = 0; i < 8; i++) acc[m][i] = (f32x4){0.f, 0.f, 0.f, 0.f};

#pragma unroll
    for (int kt = 0; kt < 12; kt++) {
        short8 ah[4], al[4];
#pragma unroll
        for (int m = 0; m < 4; m++) {
            ah[m] = *(const short8*)(aHiB + (size_t)m * 16 * KTOT + kt * 32);
            if (kt < 4) al[m] = *(const short8*)(aLoB + (size_t)m * 16 * D + kt * 32);
        }
#pragma unroll
        for (int ct = 0; ct < 8; ct++) {
            size_t wb = (((size_t)kt * 8 + ct) * 64 + lane) * 8;
            short8 bh = *(const short8*)(WpHi + wb);
            short8 bl = *(const short8*)(WpLo + wb);
#pragma unroll
            for (int m = 0; m < 4; m++) {
                acc[m][ct] = __builtin_amdgcn_mfma_f32_16x16x32_bf16(ah[m], bh, acc[m][ct], 0, 0, 0);
                acc[m][ct] = __builtin_amdgcn_mfma_f32_16x16x32_bf16(ah[m], bl, acc[m][ct], 0, 0, 0);
                if (kt < 4)
                    acc[m][ct] = __builtin_amdgcn_mfma_f32_16x16x32_bf16(al[m], bh, acc[m][ct], 0, 0, 0);
            }
        }
    }

    // epilogue: C/D layout col=lane&15, row=(lane>>4)*4+reg [m89-verified]
    int ccol = lane & 15;
#pragma unroll
    for (int m = 0; m < 4; m++) {
        int crow = r0 + m * 16 + (lane >> 4) * 4;
#pragma unroll
        for (int ct = 0; ct < 8; ct++) {
            float bb = bias[ct * 16 + ccol];
#pragma unroll
            for (int r = 0; r < 4; r++) {
                float v = fmaxf(acc[m][ct][r] + bb, 0.f);
                unsigned short h = f2bf(v);
                unsigned short l = f2bf(v - bf2f(h));
                Ahi[(size_t)(crow + r) * KTOT + ct * 16 + ccol] = h;
                XLO[(size_t)(crow + r) * D + ct * 16 + ccol] = l;
            }
        }
    }
}

// ---- classifier: out[N,8] f32 from H (Ahi cols 0..127 + XLO) ----
__global__ void __launch_bounds__(256)
k_cls(const unsigned short* __restrict__ Ahi, const unsigned short* __restrict__ XLO,
      const float* __restrict__ W, const float* __restrict__ b, float* __restrict__ out) {
    int lane = threadIdx.x & 63;
    int wid = blockIdx.x * (blockDim.x >> 6) + (threadIdx.x >> 6);
    if (wid >= NN) return;
    int cc = lane & 7;
    int kg = lane >> 3;
    const unsigned short* hH = Ahi + (size_t)wid * KTOT + kg * 16;
    const unsigned short* hL = XLO + (size_t)wid * D + kg * 16;
    float s = 0.f;
#pragma unroll
    for (int j = 0; j < 16; j += 2) {
        unsigned int ph = *(const unsigned int*)(hH + j);
        unsigned int pl = *(const unsigned int*)(hL + j);
        float h0 = bf2f((unsigned short)(ph & 0xffffu)) + bf2f((unsigned short)(pl & 0xffffu));
        float h1 = bf2f((unsigned short)(ph >> 16)) + bf2f((unsigned short)(pl >> 16));
        s += h0 * W[(kg * 16 + j) * 8 + cc];
        s += h1 * W[(kg * 16 + j + 1) * 8 + cc];
    }
    s += __shfl_xor(s, 8, 64);
    s += __shfl_xor(s, 16, 64);
    s += __shfl_xor(s, 32, 64);
    if (lane < 8) out[(size_t)wid * 8 + cc] = s + b[cc];
}

extern "C" void kernel_launch(void* const* d_in, const int* in_sizes, int n_in,
                              void* d_out, int out_size, void* d_ws, size_t ws_size,
                              hipStream_t stream) {
    const float* x   = (const float*)d_in[0];
    const void* ei   = d_in[1];
    const void* y    = d_in[2];
    const void* mask = d_in[3];

    char* ws = (char*)d_ws;
    size_t cur_off = 0;
    auto alloc = [&](size_t bytes) {
        size_t o = cur_off;
        cur_off = (cur_off + bytes + 255) & ~(size_t)255;
        return o;
    };

    size_t oAhi = alloc((size_t)NN_PAD * KTOT * 2);   // 77.1 MB
    size_t oXLO = alloc((size_t)NN_PAD * D * 2);      // 25.7 MB
    size_t oW1h = alloc(KTOT * D * 2);
    size_t oW1l = alloc(KTOT * D * 2);
    size_t oW2h = alloc(KTOT * D * 2);
    size_t oW2l = alloc(KTOT * D * 2);
    size_t oNT   = alloc(NN * 4);
    size_t oDEG  = alloc(NN * 4);
    size_t oOFFS = alloc((NN + 1) * 4);
    size_t oBSUM = alloc(NBS * 4);
    size_t oBPRE = alloc(NBS * 4);
    size_t oSP   = alloc((size_t)NE * 4);
    size_t oDST  = alloc((size_t)NE * 4);
    size_t oRNK  = alloc((size_t)NE * 4);
    size_t oSSRC = alloc((size_t)NE * 4);
    size_t oFLG  = alloc(256);

    unsigned short* Ahi = (unsigned short*)(ws + oAhi);
    unsigned short* XLO = (unsigned short*)(ws + oXLO);
    unsigned short* W1h = (unsigned short*)(ws + oW1h);
    unsigned short* W1l = (unsigned short*)(ws + oW1l);
    unsigned short* W2h = (unsigned short*)(ws + oW2h);
    unsigned short* W2l = (unsigned short*)(ws + oW2l);
    int* NT   = (int*)(ws + oNT);
    int* DEG  = (int*)(ws + oDEG);
    int* OFFS = (int*)(ws + oOFFS);
    int* BSUM = (int*)(ws + oBSUM);
    int* BPRE = (int*)(ws + oBPRE);
    int* SP   = (int*)(ws + oSP);
    int* DST  = (int*)(ws + oDST);
    int* RNK  = (int*)(ws + oRNK);
    int* SSRC = (int*)(ws + oSSRC);
    int* FLG  = (int*)(ws + oFLG);

    hipMemsetAsync(DEG, 0, NN * sizeof(int), stream);

    k_detect<<<1, 64, 0, stream>>>((const unsigned int*)ei, (const unsigned int*)y,
                                   (const unsigned int*)mask, FLG);
    k_prep<<<(NN + 255) / 256, 256, 0, stream>>>(FLG, y, mask, NT);
    k_conv_e<<<(NE + 255) / 256, 256, 0, stream>>>(FLG, ei, NT, SP, DST, DEG, RNK);
    k_convx<<<NN * D / 4 / 256, 256, 0, stream>>>(x, Ahi, XLO);
    k_wprep<<<(KTOT * D + 255) / 256, 256, 0, stream>>>(
        (const float*)d_in[8], (const float*)d_in[4], (const float*)d_in[5], W1h, W1l);
    k_wprep<<<(KTOT * D + 255) / 256, 256, 0, stream>>>(
        (const float*)d_in[14], (const float*)d_in[10], (const float*)d_in[11], W2h, W2l);

    k_scan_a<<<NBS, 256, 0, stream>>>(DEG, BSUM);
    k_scan_b<<<1, 128, 0, stream>>>(BSUM, BPRE, OFFS);
    k_scan_c<<<NBS, 256, 0, stream>>>(DEG, BPRE, OFFS);
    k_place<<<2048, 256, 0, stream>>>(SP, DST, RNK, OFFS, SSRC);

    // layer 1
    k_aggr<<<NN / 4, 256, 0, stream>>>(Ahi, XLO, SSRC, OFFS,
        (const float*)d_in[6], (const float*)d_in[7]);
    k_mfma<<<NN_PAD / 256, 256, 0, stream>>>(Ahi, XLO, W1h, W1l, (const float*)d_in[9]);
    // layer 2 (H in Ahi cols 0..127 + XLO)
    k_aggr<<<NN / 4, 256, 0, stream>>>(Ahi, XLO, SSRC, OFFS,
        (const float*)d_in[12], (const float*)d_in[13]);
    k_mfma<<<NN_PAD / 256, 256, 0, stream>>>(Ahi, XLO, W2h, W2l, (const float*)d_in[15]);

    k_cls<<<NN / 4, 256, 0, stream>>>(Ahi, XLO, (const float*)d_in[16],
                                      (const float*)d_in[17], (float*)d_out);
}

// Round 8
// 496.597 us; speedup vs baseline: 3.0166x; 1.0961x over previous
//
#include <hip/hip_runtime.h>
#include <hip/hip_bf16.h>
#include <cmath>

#define DEV static __device__ __forceinline__

constexpr int NN = 100000;
constexpr int NN_PAD = 100352;     // 392 * 256, pad rows never reach d_out
constexpr int NE = 1600000;
constexpr int D  = 128;
constexpr int KTOT = 384;          // [X | U | V]
constexpr int SCHUNK = 1024;
constexpr int NBS = (NN + SCHUNK - 1) / SCHUNK;   // 98

typedef __attribute__((ext_vector_type(8))) short short8;
typedef __attribute__((ext_vector_type(4))) float f32x4;

DEV float bf2f(unsigned short u) {
    unsigned int t = ((unsigned int)u) << 16;
    return __builtin_bit_cast(float, t);
}
DEV unsigned short f2bf(float f) {
    unsigned int u = __builtin_bit_cast(unsigned int, f);
    u += 0x7fffu + ((u >> 16) & 1u);   // RNE
    return (unsigned short)(u >> 16);
}
DEV unsigned int packbf(float a, float b) {
    return (unsigned int)f2bf(a) | ((unsigned int)f2bf(b) << 16);
}

// ---- int-width detection (wave-parallel) ----
__global__ void k_detect(const unsigned int* __restrict__ ew,
                         const unsigned int* __restrict__ yw,
                         const unsigned int* __restrict__ mw,
                         int* __restrict__ flags) {
    int lane = threadIdx.x & 63;
    int c_e = __popcll(__ballot(ew[2 * lane + 1] != 0u));
    int c_y = __popcll(__ballot(yw[2 * lane + 1] != 0u));
    int c_mb = __popcll(__ballot(mw[lane] > 1u));
    int c_mz = __popcll(__ballot(mw[2 * lane + 1] != 0u));
    if (lane == 0) {
        flags[1] = (c_e < 8) ? 1 : 0;
        flags[2] = (c_y < 8) ? 1 : 0;
        flags[3] = c_mb > 8 ? 2 : (c_mz < 8 ? 1 : 0);
    }
}

__global__ void k_prep(const int* __restrict__ flg, const void* __restrict__ y,
                       const void* __restrict__ mask, int* __restrict__ nt) {
    int i = blockIdx.x * blockDim.x + threadIdx.x;
    if (i >= NN) return;
    int yv = flg[2] ? (int)((const long long*)y)[i] : ((const int*)y)[i];
    int mm = flg[3] == 2 ? (int)((const unsigned char*)mask)[i]
           : flg[3] == 1 ? (int)((const long long*)mask)[i]
           : ((const int*)mask)[i];
    nt[i] = mm ? yv : 2;
}

// edges -> packed src ((s<<2)|nt[s]), dst, degree histogram + per-edge rank (fused)
__global__ void k_conv_e(const int* __restrict__ flg, const void* __restrict__ ei,
                         const int* __restrict__ nt,
                         int* __restrict__ SP, int* __restrict__ DST,
                         int* __restrict__ deg, int* __restrict__ rnk) {
    int e = blockIdx.x * blockDim.x + threadIdx.x;
    if (e >= NE) return;
    int s, d;
    if (flg[1]) {
        const long long* p = (const long long*)ei;
        s = (int)p[e]; d = (int)p[NE + e];
    } else {
        const int* p = (const int*)ei;
        s = p[e]; d = p[NE + e];
    }
    SP[e] = (s << 2) | nt[s];
    DST[e] = d;
    rnk[e] = atomicAdd(&deg[d], 1);
}

// x (f32) -> Ahi cols 0..127 (stride 384) + XLO (stride 128)
__global__ void k_convx(const float* __restrict__ x,
                        unsigned short* __restrict__ Ahi, unsigned short* __restrict__ XLO) {
    long t = blockIdx.x * (long)blockDim.x + threadIdx.x;
    long g = t * 4;
    if (g >= (long)NN * D) return;
    int n = (int)(g >> 7);
    int k = (int)(g & 127);
    float4 v = *(const float4*)(x + g);
    float vv[4] = {v.x, v.y, v.z, v.w};
    ushort4 hi, lo;
    unsigned short* hp = (unsigned short*)&hi;
    unsigned short* lp = (unsigned short*)&lo;
#pragma unroll
    for (int j = 0; j < 4; j++) {
        unsigned short h = f2bf(vv[j]);
        hp[j] = h;
        lp[j] = f2bf(vv[j] - bf2f(h));
    }
    *(ushort4*)(Ahi + (size_t)n * KTOT + k) = hi;
    *(ushort4*)(XLO + (size_t)n * D + k) = lo;
}

// weights -> B-fragment-ordered hi/lo planes (k: 0..127 Wself, 128..255 Wfr, 256..383 Wbe)
__global__ void k_wprep(const float* __restrict__ Wsf, const float* __restrict__ Wfr,
                        const float* __restrict__ Wbe,
                        unsigned short* __restrict__ WpHi, unsigned short* __restrict__ WpLo) {
    int t = blockIdx.x * blockDim.x + threadIdx.x;
    if (t >= KTOT * D) return;
    int k = t >> 7;
    int c = t & 127;
    float w = k < 128 ? Wsf[k * 128 + c]
            : k < 256 ? Wfr[(k - 128) * 128 + c]
            : Wbe[(k - 256) * 128 + c];
    unsigned short hi = f2bf(w);
    unsigned short lo = f2bf(w - bf2f(hi));
    int kt = k >> 5, kin = k & 31;
    int grp = kin >> 3, j = kin & 7;
    int ct = c >> 4, cl = c & 15;
    size_t idx = (((size_t)kt * 8 + ct) * 64 + ((grp << 4) | cl)) * 8 + j;
    WpHi[idx] = hi;
    WpLo[idx] = lo;
}

// ---- CSR scans ----
__global__ void k_scan_a(const int* __restrict__ deg, int* __restrict__ bsum) {
    __shared__ int sh[256];
    int b = blockIdx.x, t = threadIdx.x;
    int base = b * SCHUNK + t * 4;
    int s = 0;
#pragma unroll
    for (int j = 0; j < 4; j++) { int i = base + j; if (i < NN) s += deg[i]; }
    sh[t] = s; __syncthreads();
    for (int d = 128; d > 0; d >>= 1) {
        if (t < d) sh[t] += sh[t + d];
        __syncthreads();
    }
    if (t == 0) bsum[b] = sh[0];
}

__global__ void k_scan_b(const int* __restrict__ bsum, int* __restrict__ bpre,
                         int* __restrict__ offs) {
    __shared__ int sh[128];
    int t = threadIdx.x;
    int v = (t < NBS) ? bsum[t] : 0;
    int incl = v; sh[t] = incl; __syncthreads();
    for (int d = 1; d < 128; d <<= 1) {
        int add = (t >= d) ? sh[t - d] : 0;
        __syncthreads();
        incl += add; sh[t] = incl;
        __syncthreads();
    }
    if (t < NBS) bpre[t] = incl - v;
    if (t == 0) offs[NN] = NE;
}

__global__ void k_scan_c(const int* __restrict__ deg, const int* __restrict__ bpre,
                         int* __restrict__ offs) {
    __shared__ int sh[256];
    int b = blockIdx.x, t = threadIdx.x;
    int base = b * SCHUNK + t * 4;
    int v[4];
#pragma unroll
    for (int j = 0; j < 4; j++) { int i = base + j; v[j] = (i < NN) ? deg[i] : 0; }
    int tsum = v[0] + v[1] + v[2] + v[3];
    int incl = tsum; sh[t] = incl; __syncthreads();
    for (int d = 1; d < 256; d <<= 1) {
        int add = (t >= d) ? sh[t - d] : 0;
        __syncthreads();
        incl += add; sh[t] = incl;
        __syncthreads();
    }
    int ex = (incl - tsum) + bpre[b];
#pragma unroll
    for (int j = 0; j < 4; j++) {
        int i = base + j;
        if (i < NN) { offs[i] = ex; ex += v[j]; }
    }
}

// pure permutation scatter (no atomics): slot = offs[dst] + rank
__global__ void k_place(const int* __restrict__ SP, const int* __restrict__ DST,
                        const int* __restrict__ RNK, const int* __restrict__ offs,
                        int* __restrict__ ssrc) {
    for (int e = blockIdx.x * blockDim.x + threadIdx.x; e < NE; e += gridDim.x * blockDim.x) {
        int d = DST[e];
        int slot = offs[d] + RNK[e];
        __builtin_nontemporal_store(SP[e], &ssrc[slot]);
    }
}

// ---- aggregation: one wave per node; 16-lane group per edge; dwordx4 gathers ----
// lane = (eg = lane>>4 edge-subgroup, dg = lane&15 dim-group of 8 dims)
// writes U (cols 128..255) and V (cols 256..383) hi into Ahi
__global__ void __launch_bounds__(256)
k_aggr(unsigned short* __restrict__ Ahi, const unsigned short* __restrict__ XLO,
       const int* __restrict__ sp, const int* __restrict__ offs,
       const float* __restrict__ aw, const float* __restrict__ ab) {
    int lane = threadIdx.x & 63;
    int d = blockIdx.x * (blockDim.x >> 6) + (threadIdx.x >> 6);
    if (d >= NN) return;
    int eg = lane >> 4;
    int dg = lane & 15;
    int k0 = dg * 8;

    // alpha = sigmoid(X[d] . aw + ab)  (hi from Ahi, lo from XLO), 2 dims/lane
    int ak = lane * 2;
    unsigned int whi = *(const unsigned int*)(Ahi + (size_t)d * KTOT + ak);
    unsigned int wlo = *(const unsigned int*)(XLO + (size_t)d * D + ak);
    float xa = bf2f((unsigned short)(whi & 0xffffu)) + bf2f((unsigned short)(wlo & 0xffffu));
    float xb = bf2f((unsigned short)(whi >> 16)) + bf2f((unsigned short)(wlo >> 16));
    float dot = xa * aw[ak] + xb * aw[ak + 1];
#pragma unroll
    for (int m = 32; m > 0; m >>= 1) dot += __shfl_xor(dot, m, 64);
    float a = 1.0f / (1.0f + expf(-(dot + ab[0])));
    float oma = 1.0f - a;

    float u[8], v[8];
#pragma unroll
    for (int q = 0; q < 8; q++) { u[q] = 0.f; v[q] = 0.f; }

    int e0 = offs[d];
    int n = offs[d + 1] - e0;
    const int* spp = sp + e0;
    for (int base = 0; base < n; base += 8) {
        // two 4-edge halves -> 2 independent gathers per lane
        int iA = base + eg;
        int iB = base + 4 + eg;
        int cA = iA < n ? iA : 0;
        int cB = iB < n ? iB : 0;
        int pkA = spp[cA];
        int pkB = spp[cB];
        int bA = pkA & 3, sA = pkA >> 2;
        int bB = pkB & 3, sB = pkB >> 2;
        float cuA = iA < n ? ((bA == 1) ? 1.f : (bA == 0 ? 0.f : a)) : 0.f;
        float cvA = iA < n ? ((bA == 0) ? 1.f : (bA == 1 ? 0.f : oma)) : 0.f;
        float cuB = iB < n ? ((bB == 1) ? 1.f : (bB == 0 ? 0.f : a)) : 0.f;
        float cvB = iB < n ? ((bB == 0) ? 1.f : (bB == 1 ? 0.f : oma)) : 0.f;
        uint4 wA = *(const uint4*)(Ahi + (size_t)sA * KTOT + k0);
        uint4 wB = *(const uint4*)(Ahi + (size_t)sB * KTOT + k0);
        const unsigned int* wa = (const unsigned int*)&wA;
        const unsigned int* wb = (const unsigned int*)&wB;
#pragma unroll
        for (int q = 0; q < 4; q++) {
            float a0 = bf2f((unsigned short)(wa[q] & 0xffffu));
            float a1 = bf2f((unsigned short)(wa[q] >> 16));
            float b0 = bf2f((unsigned short)(wb[q] & 0xffffu));
            float b1 = bf2f((unsigned short)(wb[q] >> 16));
            u[2 * q]     += cuA * a0 + cuB * b0;
            u[2 * q + 1] += cuA * a1 + cuB * b1;
            v[2 * q]     += cvA * a0 + cvB * b0;
            v[2 * q + 1] += cvA * a1 + cvB * b1;
        }
    }

    // fold the 4 edge-subgroups (lanes dg, dg+16, dg+32, dg+48)
#pragma unroll
    for (int q = 0; q < 8; q++) {
        u[q] += __shfl_xor(u[q], 16, 64);
        u[q] += __shfl_xor(u[q], 32, 64);
        v[q] += __shfl_xor(v[q], 16, 64);
        v[q] += __shfl_xor(v[q], 32, 64);
    }
    if (eg == 0) {
        unsigned int up[4], vp[4];
#pragma unroll
        for (int q = 0; q < 4; q++) {
            up[q] = packbf(u[2 * q], u[2 * q + 1]);
            vp[q] = packbf(v[2 * q], v[2 * q + 1]);
        }
        *(uint4*)(Ahi + (size_t)d * KTOT + 128 + k0) = *(uint4*)up;
        *(uint4*)(Ahi + (size_t)d * KTOT + 256 + k0) = *(uint4*)vp;
    }
}

// ---- MFMA GEMM: relu(A@Wcat + bias); 64 rows/wave; A-lo only for X k-tiles ----
__global__ void __launch_bounds__(256)
k_mfma(unsigned short* __restrict__ Ahi, unsigned short* __restrict__ XLO,
       const unsigned short* __restrict__ WpHi, const unsigned short* __restrict__ WpLo,
       const float* __restrict__ bias) {
    int lane = threadIdx.x & 63;
    int wave = threadIdx.x >> 6;
    int r0 = blockIdx.x * 256 + wave * 64;

    int mrow = lane & 15, kgrp = lane >> 4;
    const unsigned short* aHiB = Ahi + (size_t)(r0 + mrow) * KTOT + kgrp * 8;
    const unsigned short* aLoB = XLO + (size_t)(r0 + mrow) * D + kgrp * 8;

    f32x4 acc[4][8];
#pragma unroll
    for (int m = 0; m < 4; m++)
#pragma unroll
        for (int i = 0; i < 8; i++) acc[m][i] = (f32x4){0.f, 0.f, 0.f, 0.f};

#pragma unroll
    for (int kt = 0; kt < 12; kt++) {
        short8 ah[4], al[4];
#pragma unroll
        for (int m = 0; m < 4; m++) {
            ah[m] = *(const short8*)(aHiB + (size_t)m * 16 * KTOT + kt * 32);
            if (kt < 4) al[m] = *(const short8*)(aLoB + (size_t)m * 16 * D + kt * 32);
        }
#pragma unroll
        for (int ct = 0; ct < 8; ct++) {
            size_t wb = (((size_t)kt * 8 + ct) * 64 + lane) * 8;
            short8 bh = *(const short8*)(WpHi + wb);
            short8 bl = *(const short8*)(WpLo + wb);
#pragma unroll
            for (int m = 0; m < 4; m++) {
                acc[m][ct] = __builtin_amdgcn_mfma_f32_16x16x32_bf16(ah[m], bh, acc[m][ct], 0, 0, 0);
                acc[m][ct] = __builtin_amdgcn_mfma_f32_16x16x32_bf16(ah[m], bl, acc[m][ct], 0, 0, 0);
                if (kt < 4)
                    acc[m][ct] = __builtin_amdgcn_mfma_f32_16x16x32_bf16(al[m], bh, acc[m][ct], 0, 0, 0);
            }
        }
    }

    // epilogue: C/D layout col=lane&15, row=(lane>>4)*4+reg [m89-verified]
    int ccol = lane & 15;
#pragma unroll
    for (int m = 0; m < 4; m++) {
        int crow = r0 + m * 16 + (lane >> 4) * 4;
#pragma unroll
        for (int ct = 0; ct < 8; ct++) {
            float bb = bias[ct * 16 + ccol];
#pragma unroll
            for (int r = 0; r < 4; r++) {
                float v = fmaxf(acc[m][ct][r] + bb, 0.f);
                unsigned short h = f2bf(v);
                unsigned short l = f2bf(v - bf2f(h));
                Ahi[(size_t)(crow + r) * KTOT + ct * 16 + ccol] = h;
                XLO[(size_t)(crow + r) * D + ct * 16 + ccol] = l;
            }
        }
    }
}

// ---- classifier: out[N,8] f32 from H (Ahi cols 0..127 + XLO) ----
__global__ void __launch_bounds__(256)
k_cls(const unsigned short* __restrict__ Ahi, const unsigned short* __restrict__ XLO,
      const float* __restrict__ W, const float* __restrict__ b, float* __restrict__ out) {
    int lane = threadIdx.x & 63;
    int wid = blockIdx.x * (blockDim.x >> 6) + (threadIdx.x >> 6);
    if (wid >= NN) return;
    int cc = lane & 7;
    int kg = lane >> 3;
    const unsigned short* hH = Ahi + (size_t)wid * KTOT + kg * 16;
    const unsigned short* hL = XLO + (size_t)wid * D + kg * 16;
    float s = 0.f;
#pragma unroll
    for (int j = 0; j < 16; j += 2) {
        unsigned int ph = *(const unsigned int*)(hH + j);
        unsigned int pl = *(const unsigned int*)(hL + j);
        float h0 = bf2f((unsigned short)(ph & 0xffffu)) + bf2f((unsigned short)(pl & 0xffffu));
        float h1 = bf2f((unsigned short)(ph >> 16)) + bf2f((unsigned short)(pl >> 16));
        s += h0 * W[(kg * 16 + j) * 8 + cc];
        s += h1 * W[(kg * 16 + j + 1) * 8 + cc];
    }
    s += __shfl_xor(s, 8, 64);
    s += __shfl_xor(s, 16, 64);
    s += __shfl_xor(s, 32, 64);
    if (lane < 8) out[(size_t)wid * 8 + cc] = s + b[cc];
}

extern "C" void kernel_launch(void* const* d_in, const int* in_sizes, int n_in,
                              void* d_out, int out_size, void* d_ws, size_t ws_size,
                              hipStream_t stream) {
    const float* x   = (const float*)d_in[0];
    const void* ei   = d_in[1];
    const void* y    = d_in[2];
    const void* mask = d_in[3];

    char* ws = (char*)d_ws;
    size_t cur_off = 0;
    auto alloc = [&](size_t bytes) {
        size_t o = cur_off;
        cur_off = (cur_off + bytes + 255) & ~(size_t)255;
        return o;
    };

    size_t oAhi = alloc((size_t)NN_PAD * KTOT * 2);   // 77.1 MB
    size_t oXLO = alloc((size_t)NN_PAD * D * 2);      // 25.7 MB
    size_t oW1h = alloc(KTOT * D * 2);
    size_t oW1l = alloc(KTOT * D * 2);
    size_t oW2h = alloc(KTOT * D * 2);
    size_t oW2l = alloc(KTOT * D * 2);
    size_t oNT   = alloc(NN * 4);
    size_t oDEG  = alloc(NN * 4);
    size_t oOFFS = alloc((NN + 1) * 4);
    size_t oBSUM = alloc(NBS * 4);
    size_t oBPRE = alloc(NBS * 4);
    size_t oSP   = alloc((size_t)NE * 4);
    size_t oDST  = alloc((size_t)NE * 4);
    size_t oRNK  = alloc((size_t)NE * 4);
    size_t oSSRC = alloc((size_t)NE * 4);
    size_t oFLG  = alloc(256);

    unsigned short* Ahi = (unsigned short*)(ws + oAhi);
    unsigned short* XLO = (unsigned short*)(ws + oXLO);
    unsigned short* W1h = (unsigned short*)(ws + oW1h);
    unsigned short* W1l = (unsigned short*)(ws + oW1l);
    unsigned short* W2h = (unsigned short*)(ws + oW2h);
    unsigned short* W2l = (unsigned short*)(ws + oW2l);
    int* NT   = (int*)(ws + oNT);
    int* DEG  = (int*)(ws + oDEG);
    int* OFFS = (int*)(ws + oOFFS);
    int* BSUM = (int*)(ws + oBSUM);
    int* BPRE = (int*)(ws + oBPRE);
    int* SP   = (int*)(ws + oSP);
    int* DST  = (int*)(ws + oDST);
    int* RNK  = (int*)(ws + oRNK);
    int* SSRC = (int*)(ws + oSSRC);
    int* FLG  = (int*)(ws + oFLG);

    hipMemsetAsync(DEG, 0, NN * sizeof(int), stream);

    k_detect<<<1, 64, 0, stream>>>((const unsigned int*)ei, (const unsigned int*)y,
                                   (const unsigned int*)mask, FLG);
    k_prep<<<(NN + 255) / 256, 256, 0, stream>>>(FLG, y, mask, NT);
    k_conv_e<<<(NE + 255) / 256, 256, 0, stream>>>(FLG, ei, NT, SP, DST, DEG, RNK);
    k_convx<<<NN * D / 4 / 256, 256, 0, stream>>>(x, Ahi, XLO);
    k_wprep<<<(KTOT * D + 255) / 256, 256, 0, stream>>>(
        (const float*)d_in[8], (const float*)d_in[4], (const float*)d_in[5], W1h, W1l);
    k_wprep<<<(KTOT * D + 255) / 256, 256, 0, stream>>>(
        (const float*)d_in[14], (const float*)d_in[10], (const float*)d_in[11], W2h, W2l);

    k_scan_a<<<NBS, 256, 0, stream>>>(DEG, BSUM);
    k_scan_b<<<1, 128, 0, stream>>>(BSUM, BPRE, OFFS);
    k_scan_c<<<NBS, 256, 0, stream>>>(DEG, BPRE, OFFS);
    k_place<<<2048, 256, 0, stream>>>(SP, DST, RNK, OFFS, SSRC);

    // layer 1
    k_aggr<<<NN / 4, 256, 0, stream>>>(Ahi, XLO, SSRC, OFFS,
        (const float*)d_in[6], (const float*)d_in[7]);
    k_mfma<<<NN_PAD / 256, 256, 0, stream>>>(Ahi, XLO, W1h, W1l, (const float*)d_in[9]);
    // layer 2 (H in Ahi cols 0..127 + XLO)
    k_aggr<<<NN / 4, 256, 0, stream>>>(Ahi, XLO, SSRC, OFFS,
        (const float*)d_in[12], (const float*)d_in[13]);
    k_mfma<<<NN_PAD / 256, 256, 0, stream>>>(Ahi, XLO, W2h, W2l, (const float*)d_in[15]);

    k_cls<<<NN / 4, 256, 0, stream>>>(Ahi, XLO, (const float*)d_in[16],
                                      (const float*)d_in[17], (float*)d_out);
}

// Round 9
// 461.264 us; speedup vs baseline: 3.2476x; 1.0766x over previous
//
#include <hip/hip_runtime.h>
#include <hip/hip_bf16.h>
#include <cmath>

#define DEV static __device__ __forceinline__

constexpr int NN = 100000;
constexpr int NN_PAD = 100352;     // 784 * 128, pad rows never reach d_out
constexpr int NE = 1600000;
constexpr int D  = 128;
constexpr int KTOT = 384;          // [X | U | V]
constexpr int SCHUNK = 1024;
constexpr int NBS = (NN + SCHUNK - 1) / SCHUNK;   // 98

typedef __attribute__((ext_vector_type(8))) short short8;
typedef __attribute__((ext_vector_type(4))) float f32x4;

DEV float bf2f(unsigned short u) {
    unsigned int t = ((unsigned int)u) << 16;
    return __builtin_bit_cast(float, t);
}
DEV unsigned short f2bf(float f) {
    unsigned int u = __builtin_bit_cast(unsigned int, f);
    u += 0x7fffu + ((u >> 16) & 1u);   // RNE
    return (unsigned short)(u >> 16);
}
DEV unsigned int packbf(float a, float b) {
    return (unsigned int)f2bf(a) | ((unsigned int)f2bf(b) << 16);
}

// ---- int-width detection (wave-parallel) ----
__global__ void k_detect(const unsigned int* __restrict__ ew,
                         const unsigned int* __restrict__ yw,
                         const unsigned int* __restrict__ mw,
                         int* __restrict__ flags) {
    int lane = threadIdx.x & 63;
    int c_e = __popcll(__ballot(ew[2 * lane + 1] != 0u));
    int c_y = __popcll(__ballot(yw[2 * lane + 1] != 0u));
    int c_mb = __popcll(__ballot(mw[lane] > 1u));
    int c_mz = __popcll(__ballot(mw[2 * lane + 1] != 0u));
    if (lane == 0) {
        flags[1] = (c_e < 8) ? 1 : 0;
        flags[2] = (c_y < 8) ? 1 : 0;
        flags[3] = c_mb > 8 ? 2 : (c_mz < 8 ? 1 : 0);
    }
}

__global__ void k_prep(const int* __restrict__ flg, const void* __restrict__ y,
                       const void* __restrict__ mask, int* __restrict__ nt) {
    int i = blockIdx.x * blockDim.x + threadIdx.x;
    if (i >= NN) return;
    int yv = flg[2] ? (int)((const long long*)y)[i] : ((const int*)y)[i];
    int mm = flg[3] == 2 ? (int)((const unsigned char*)mask)[i]
           : flg[3] == 1 ? (int)((const long long*)mask)[i]
           : ((const int*)mask)[i];
    nt[i] = mm ? yv : 2;
}

// edges -> packed src ((s<<2)|nt[s]), dst, degree histogram + per-edge rank (fused)
__global__ void k_conv_e(const int* __restrict__ flg, const void* __restrict__ ei,
                         const int* __restrict__ nt,
                         int* __restrict__ SP, int* __restrict__ DST,
                         int* __restrict__ deg, int* __restrict__ rnk) {
    int e = blockIdx.x * blockDim.x + threadIdx.x;
    if (e >= NE) return;
    int s, d;
    if (flg[1]) {
        const long long* p = (const long long*)ei;
        s = (int)p[e]; d = (int)p[NE + e];
    } else {
        const int* p = (const int*)ei;
        s = p[e]; d = p[NE + e];
    }
    SP[e] = (s << 2) | nt[s];
    DST[e] = d;
    rnk[e] = atomicAdd(&deg[d], 1);
}

// x (f32) -> Ahi cols 0..127 (stride 384) + XLO (stride 128)
__global__ void k_convx(const float* __restrict__ x,
                        unsigned short* __restrict__ Ahi, unsigned short* __restrict__ XLO) {
    long t = blockIdx.x * (long)blockDim.x + threadIdx.x;
    long g = t * 4;
    if (g >= (long)NN * D) return;
    int n = (int)(g >> 7);
    int k = (int)(g & 127);
    float4 v = *(const float4*)(x + g);
    float vv[4] = {v.x, v.y, v.z, v.w};
    ushort4 hi, lo;
    unsigned short* hp = (unsigned short*)&hi;
    unsigned short* lp = (unsigned short*)&lo;
#pragma unroll
    for (int j = 0; j < 4; j++) {
        unsigned short h = f2bf(vv[j]);
        hp[j] = h;
        lp[j] = f2bf(vv[j] - bf2f(h));
    }
    *(ushort4*)(Ahi + (size_t)n * KTOT + k) = hi;
    *(ushort4*)(XLO + (size_t)n * D + k) = lo;
}

// weights -> B-fragment-ordered hi/lo planes (k: 0..127 Wself, 128..255 Wfr, 256..383 Wbe)
__global__ void k_wprep(const float* __restrict__ Wsf, const float* __restrict__ Wfr,
                        const float* __restrict__ Wbe,
                        unsigned short* __restrict__ WpHi, unsigned short* __restrict__ WpLo) {
    int t = blockIdx.x * blockDim.x + threadIdx.x;
    if (t >= KTOT * D) return;
    int k = t >> 7;
    int c = t & 127;
    float w = k < 128 ? Wsf[k * 128 + c]
            : k < 256 ? Wfr[(k - 128) * 128 + c]
            : Wbe[(k - 256) * 128 + c];
    unsigned short hi = f2bf(w);
    unsigned short lo = f2bf(w - bf2f(hi));
    int kt = k >> 5, kin = k & 31;
    int grp = kin >> 3, j = kin & 7;
    int ct = c >> 4, cl = c & 15;
    size_t idx = (((size_t)kt * 8 + ct) * 64 + ((grp << 4) | cl)) * 8 + j;
    WpHi[idx] = hi;
    WpLo[idx] = lo;
}

// ---- CSR scans ----
__global__ void k_scan_a(const int* __restrict__ deg, int* __restrict__ bsum) {
    __shared__ int sh[256];
    int b = blockIdx.x, t = threadIdx.x;
    int base = b * SCHUNK + t * 4;
    int s = 0;
#pragma unroll
    for (int j = 0; j < 4; j++) { int i = base + j; if (i < NN) s += deg[i]; }
    sh[t] = s; __syncthreads();
    for (int d = 128; d > 0; d >>= 1) {
        if (t < d) sh[t] += sh[t + d];
        __syncthreads();
    }
    if (t == 0) bsum[b] = sh[0];
}

__global__ void k_scan_b(const int* __restrict__ bsum, int* __restrict__ bpre,
                         int* __restrict__ offs) {
    __shared__ int sh[128];
    int t = threadIdx.x;
    int v = (t < NBS) ? bsum[t] : 0;
    int incl = v; sh[t] = incl; __syncthreads();
    for (int d = 1; d < 128; d <<= 1) {
        int add = (t >= d) ? sh[t - d] : 0;
        __syncthreads();
        incl += add; sh[t] = incl;
        __syncthreads();
    }
    if (t < NBS) bpre[t] = incl - v;
    if (t == 0) offs[NN] = NE;
}

__global__ void k_scan_c(const int* __restrict__ deg, const int* __restrict__ bpre,
                         int* __restrict__ offs) {
    __shared__ int sh[256];
    int b = blockIdx.x, t = threadIdx.x;
    int base = b * SCHUNK + t * 4;
    int v[4];
#pragma unroll
    for (int j = 0; j < 4; j++) { int i = base + j; v[j] = (i < NN) ? deg[i] : 0; }
    int tsum = v[0] + v[1] + v[2] + v[3];
    int incl = tsum; sh[t] = incl; __syncthreads();
    for (int d = 1; d < 256; d <<= 1) {
        int add = (t >= d) ? sh[t - d] : 0;
        __syncthreads();
        incl += add; sh[t] = incl;
        __syncthreads();
    }
    int ex = (incl - tsum) + bpre[b];
#pragma unroll
    for (int j = 0; j < 4; j++) {
        int i = base + j;
        if (i < NN) { offs[i] = ex; ex += v[j]; }
    }
}

// pure permutation scatter (no atomics): slot = offs[dst] + rank
__global__ void k_place(const int* __restrict__ SP, const int* __restrict__ DST,
                        const int* __restrict__ RNK, const int* __restrict__ offs,
                        int* __restrict__ ssrc) {
    for (int e = blockIdx.x * blockDim.x + threadIdx.x; e < NE; e += gridDim.x * blockDim.x) {
        int d = DST[e];
        int slot = offs[d] + RNK[e];
        __builtin_nontemporal_store(SP[e], &ssrc[slot]);
    }
}

// ---- aggregation: one wave per node; 16-lane group per edge; dwordx4 gathers ----
__global__ void __launch_bounds__(256)
k_aggr(unsigned short* __restrict__ Ahi, const unsigned short* __restrict__ XLO,
       const int* __restrict__ sp, const int* __restrict__ offs,
       const float* __restrict__ aw, const float* __restrict__ ab) {
    int lane = threadIdx.x & 63;
    int d = blockIdx.x * (blockDim.x >> 6) + (threadIdx.x >> 6);
    if (d >= NN) return;
    int eg = lane >> 4;
    int dg = lane & 15;
    int k0 = dg * 8;

    // alpha = sigmoid(X[d] . aw + ab)  (hi from Ahi, lo from XLO), 2 dims/lane
    int ak = lane * 2;
    unsigned int whi = *(const unsigned int*)(Ahi + (size_t)d * KTOT + ak);
    unsigned int wlo = *(const unsigned int*)(XLO + (size_t)d * D + ak);
    float xa = bf2f((unsigned short)(whi & 0xffffu)) + bf2f((unsigned short)(wlo & 0xffffu));
    float xb = bf2f((unsigned short)(whi >> 16)) + bf2f((unsigned short)(wlo >> 16));
    float dot = xa * aw[ak] + xb * aw[ak + 1];
#pragma unroll
    for (int m = 32; m > 0; m >>= 1) dot += __shfl_xor(dot, m, 64);
    float a = 1.0f / (1.0f + expf(-(dot + ab[0])));
    float oma = 1.0f - a;

    float u[8], v[8];
#pragma unroll
    for (int q = 0; q < 8; q++) { u[q] = 0.f; v[q] = 0.f; }

    int e0 = offs[d];
    int n = offs[d + 1] - e0;
    const int* spp = sp + e0;
    for (int base = 0; base < n; base += 8) {
        int iA = base + eg;
        int iB = base + 4 + eg;
        int cA = iA < n ? iA : 0;
        int cB = iB < n ? iB : 0;
        int pkA = spp[cA];
        int pkB = spp[cB];
        int bA = pkA & 3, sA = pkA >> 2;
        int bB = pkB & 3, sB = pkB >> 2;
        float cuA = iA < n ? ((bA == 1) ? 1.f : (bA == 0 ? 0.f : a)) : 0.f;
        float cvA = iA < n ? ((bA == 0) ? 1.f : (bA == 1 ? 0.f : oma)) : 0.f;
        float cuB = iB < n ? ((bB == 1) ? 1.f : (bB == 0 ? 0.f : a)) : 0.f;
        float cvB = iB < n ? ((bB == 0) ? 1.f : (bB == 1 ? 0.f : oma)) : 0.f;
        uint4 wA = *(const uint4*)(Ahi + (size_t)sA * KTOT + k0);
        uint4 wB = *(const uint4*)(Ahi + (size_t)sB * KTOT + k0);
        const unsigned int* wa = (const unsigned int*)&wA;
        const unsigned int* wb = (const unsigned int*)&wB;
#pragma unroll
        for (int q = 0; q < 4; q++) {
            float a0 = bf2f((unsigned short)(wa[q] & 0xffffu));
            float a1 = bf2f((unsigned short)(wa[q] >> 16));
            float b0 = bf2f((unsigned short)(wb[q] & 0xffffu));
            float b1 = bf2f((unsigned short)(wb[q] >> 16));
            u[2 * q]     += cuA * a0 + cuB * b0;
            u[2 * q + 1] += cuA * a1 + cuB * b1;
            v[2 * q]     += cvA * a0 + cvB * b0;
            v[2 * q + 1] += cvA * a1 + cvB * b1;
        }
    }

#pragma unroll
    for (int q = 0; q < 8; q++) {
        u[q] += __shfl_xor(u[q], 16, 64);
        u[q] += __shfl_xor(u[q], 32, 64);
        v[q] += __shfl_xor(v[q], 16, 64);
        v[q] += __shfl_xor(v[q], 32, 64);
    }
    if (eg == 0) {
        unsigned int up[4], vp[4];
#pragma unroll
        for (int q = 0; q < 4; q++) {
            up[q] = packbf(u[2 * q], u[2 * q + 1]);
            vp[q] = packbf(v[2 * q], v[2 * q + 1]);
        }
        *(uint4*)(Ahi + (size_t)d * KTOT + 128 + k0) = *(uint4*)up;
        *(uint4*)(Ahi + (size_t)d * KTOT + 256 + k0) = *(uint4*)vp;
    }
}

// ---- MFMA GEMM v3: LDS-staged B, 4-wave block over 128 rows (32/wave) ----
// relu(A@Wcat + bias); B kt-tiles (16KB) double-buffered in LDS; A-lo only kt<4.
__global__ void __launch_bounds__(256)
k_mfma(unsigned short* __restrict__ Ahi, unsigned short* __restrict__ XLO,
       const unsigned short* __restrict__ WpHi, const unsigned short* __restrict__ WpLo,
       const float* __restrict__ bias) {
    __shared__ unsigned short ldsB[2][2][4096];   // [buf][hi/lo][kt-tile] = 32 KB
    int t = threadIdx.x;
    int lane = t & 63;
    int wave = t >> 6;
    int r0 = blockIdx.x * 128 + wave * 32;        // grid is full: NN_PAD = 784*128

    int mrow = lane & 15, kgrp = lane >> 4;
    const unsigned short* aHiB = Ahi + (size_t)(r0 + mrow) * KTOT + kgrp * 8;
    const unsigned short* aLoB = XLO + (size_t)(r0 + mrow) * D + kgrp * 8;

    f32x4 acc[2][8];
#pragma unroll
    for (int m = 0; m < 2; m++)
#pragma unroll
        for (int i = 0; i < 8; i++) acc[m][i] = (f32x4){0.f, 0.f, 0.f, 0.f};

    // stage kt=0 into buf 0
    {
        int o = t * 8;
        *(uint4*)&ldsB[0][0][o]        = *(const uint4*)(WpHi + o);
        *(uint4*)&ldsB[0][0][o + 2048] = *(const uint4*)(WpHi + o + 2048);
        *(uint4*)&ldsB[0][1][o]        = *(const uint4*)(WpLo + o);
        *(uint4*)&ldsB[0][1][o + 2048] = *(const uint4*)(WpLo + o + 2048);
    }
    __syncthreads();

    int buf = 0;
#pragma unroll
    for (int kt = 0; kt < 12; kt++) {
        if (kt < 11) {
            int src = (kt + 1) * 4096 + t * 8;
            int o = t * 8;
            *(uint4*)&ldsB[buf ^ 1][0][o]        = *(const uint4*)(WpHi + src);
            *(uint4*)&ldsB[buf ^ 1][0][o + 2048] = *(const uint4*)(WpHi + src + 2048);
            *(uint4*)&ldsB[buf ^ 1][1][o]        = *(const uint4*)(WpLo + src);
            *(uint4*)&ldsB[buf ^ 1][1][o + 2048] = *(const uint4*)(WpLo + src + 2048);
        }
        short8 ah[2], al[2];
#pragma unroll
        for (int m = 0; m < 2; m++) {
            ah[m] = *(const short8*)(aHiB + (size_t)m * 16 * KTOT + kt * 32);
            if (kt < 4) al[m] = *(const short8*)(aLoB + (size_t)m * 16 * D + kt * 32);
        }
#pragma unroll
        for (int ct = 0; ct < 8; ct++) {
            short8 bh = *(const short8*)&ldsB[buf][0][ct * 512 + lane * 8];
            short8 bl = *(const short8*)&ldsB[buf][1][ct * 512 + lane * 8];
#pragma unroll
            for (int m = 0; m < 2; m++) {
                acc[m][ct] = __builtin_amdgcn_mfma_f32_16x16x32_bf16(ah[m], bh, acc[m][ct], 0, 0, 0);
                acc[m][ct] = __builtin_amdgcn_mfma_f32_16x16x32_bf16(ah[m], bl, acc[m][ct], 0, 0, 0);
                if (kt < 4)
                    acc[m][ct] = __builtin_amdgcn_mfma_f32_16x16x32_bf16(al[m], bh, acc[m][ct], 0, 0, 0);
            }
        }
        __syncthreads();
        buf ^= 1;
    }

    // epilogue: C/D layout col=lane&15, row=(lane>>4)*4+reg [m89-verified]
    int ccol = lane & 15;
#pragma unroll
    for (int m = 0; m < 2; m++) {
        int crow = r0 + m * 16 + (lane >> 4) * 4;
#pragma unroll
        for (int ct = 0; ct < 8; ct++) {
            float bb = bias[ct * 16 + ccol];
#pragma unroll
            for (int r = 0; r < 4; r++) {
                float v = fmaxf(acc[m][ct][r] + bb, 0.f);
                unsigned short h = f2bf(v);
                unsigned short l = f2bf(v - bf2f(h));
                Ahi[(size_t)(crow + r) * KTOT + ct * 16 + ccol] = h;
                XLO[(size_t)(crow + r) * D + ct * 16 + ccol] = l;
            }
        }
    }
}

// ---- classifier: out[N,8] f32 from H (Ahi cols 0..127 + XLO) ----
__global__ void __launch_bounds__(256)
k_cls(const unsigned short* __restrict__ Ahi, const unsigned short* __restrict__ XLO,
      const float* __restrict__ W, const float* __restrict__ b, float* __restrict__ out) {
    int lane = threadIdx.x & 63;
    int wid = blockIdx.x * (blockDim.x >> 6) + (threadIdx.x >> 6);
    if (wid >= NN) return;
    int cc = lane & 7;
    int kg = lane >> 3;
    const unsigned short* hH = Ahi + (size_t)wid * KTOT + kg * 16;
    const unsigned short* hL = XLO + (size_t)wid * D + kg * 16;
    float s = 0.f;
#pragma unroll
    for (int j = 0; j < 16; j += 2) {
        unsigned int ph = *(const unsigned int*)(hH + j);
        unsigned int pl = *(const unsigned int*)(hL + j);
        float h0 = bf2f((unsigned short)(ph & 0xffffu)) + bf2f((unsigned short)(pl & 0xffffu));
        float h1 = bf2f((unsigned short)(ph >> 16)) + bf2f((unsigned short)(pl >> 16));
        s += h0 * W[(kg * 16 + j) * 8 + cc];
        s += h1 * W[(kg * 16 + j + 1) * 8 + cc];
    }
    s += __shfl_xor(s, 8, 64);
    s += __shfl_xor(s, 16, 64);
    s += __shfl_xor(s, 32, 64);
    if (lane < 8) out[(size_t)wid * 8 + cc] = s + b[cc];
}

extern "C" void kernel_launch(void* const* d_in, const int* in_sizes, int n_in,
                              void* d_out, int out_size, void* d_ws, size_t ws_size,
                              hipStream_t stream) {
    const float* x   = (const float*)d_in[0];
    const void* ei   = d_in[1];
    const void* y    = d_in[2];
    const void* mask = d_in[3];

    char* ws = (char*)d_ws;
    size_t cur_off = 0;
    auto alloc = [&](size_t bytes) {
        size_t o = cur_off;
        cur_off = (cur_off + bytes + 255) & ~(size_t)255;
        return o;
    };

    size_t oAhi = alloc((size_t)NN_PAD * KTOT * 2);   // 77.1 MB
    size_t oXLO = alloc((size_t)NN_PAD * D * 2);      // 25.7 MB
    size_t oW1h = alloc(KTOT * D * 2);
    size_t oW1l = alloc(KTOT * D * 2);
    size_t oW2h = alloc(KTOT * D * 2);
    size_t oW2l = alloc(KTOT * D * 2);
    size_t oNT   = alloc(NN * 4);
    size_t oDEG  = alloc(NN * 4);
    size_t oOFFS = alloc((NN + 1) * 4);
    size_t oBSUM = alloc(NBS * 4);
    size_t oBPRE = alloc(NBS * 4);
    size_t oSP   = alloc((size_t)NE * 4);
    size_t oDST  = alloc((size_t)NE * 4);
    size_t oRNK  = alloc((size_t)NE * 4);
    size_t oSSRC = alloc((size_t)NE * 4);
    size_t oFLG  = alloc(256);

    unsigned short* Ahi = (unsigned short*)(ws + oAhi);
    unsigned short* XLO = (unsigned short*)(ws + oXLO);
    unsigned short* W1h = (unsigned short*)(ws + oW1h);
    unsigned short* W1l = (unsigned short*)(ws + oW1l);
    unsigned short* W2h = (unsigned short*)(ws + oW2h);
    unsigned short* W2l = (unsigned short*)(ws + oW2l);
    int* NT   = (int*)(ws + oNT);
    int* DEG  = (int*)(ws + oDEG);
    int* OFFS = (int*)(ws + oOFFS);
    int* BSUM = (int*)(ws + oBSUM);
    int* BPRE = (int*)(ws + oBPRE);
    int* SP   = (int*)(ws + oSP);
    int* DST  = (int*)(ws + oDST);
    int* RNK  = (int*)(ws + oRNK);
    int* SSRC = (int*)(ws + oSSRC);
    int* FLG  = (int*)(ws + oFLG);

    hipMemsetAsync(DEG, 0, NN * sizeof(int), stream);

    k_detect<<<1, 64, 0, stream>>>((const unsigned int*)ei, (const unsigned int*)y,
                                   (const unsigned int*)mask, FLG);
    k_prep<<<(NN + 255) / 256, 256, 0, stream>>>(FLG, y, mask, NT);
    k_conv_e<<<(NE + 255) / 256, 256, 0, stream>>>(FLG, ei, NT, SP, DST, DEG, RNK);
    k_convx<<<NN * D / 4 / 256, 256, 0, stream>>>(x, Ahi, XLO);
    k_wprep<<<(KTOT * D + 255) / 256, 256, 0, stream>>>(
        (const float*)d_in[8], (const float*)d_in[4], (const float*)d_in[5], W1h, W1l);
    k_wprep<<<(KTOT * D + 255) / 256, 256, 0, stream>>>(
        (const float*)d_in[14], (const float*)d_in[10], (const float*)d_in[11], W2h, W2l);

    k_scan_a<<<NBS, 256, 0, stream>>>(DEG, BSUM);
    k_scan_b<<<1, 128, 0, stream>>>(BSUM, BPRE, OFFS);
    k_scan_c<<<NBS, 256, 0, stream>>>(DEG, BPRE, OFFS);
    k_place<<<2048, 256, 0, stream>>>(SP, DST, RNK, OFFS, SSRC);

    // layer 1
    k_aggr<<<NN / 4, 256, 0, stream>>>(Ahi, XLO, SSRC, OFFS,
        (const float*)d_in[6], (const float*)d_in[7]);
    k_mfma<<<NN_PAD / 128, 256, 0, stream>>>(Ahi, XLO, W1h, W1l, (const float*)d_in[9]);
    // layer 2 (H in Ahi cols 0..127 + XLO)
    k_aggr<<<NN / 4, 256, 0, stream>>>(Ahi, XLO, SSRC, OFFS,
        (const float*)d_in[12], (const float*)d_in[13]);
    k_mfma<<<NN_PAD / 128, 256, 0, stream>>>(Ahi, XLO, W2h, W2l, (const float*)d_in[15]);

    k_cls<<<NN / 4, 256, 0, stream>>>(Ahi, XLO, (const float*)d_in[16],
                                      (const float*)d_in[17], (float*)d_out);
}